// Round 5
// baseline (4333.518 us; speedup 1.0000x reference)
//
#include <hip/hip_runtime.h>
#include <hip/hip_bf16.h>

// ---------------- constants ----------------
#define NB   4
#define DIM  128
#define KC   64
#define HH   48
#define WW   900
#define WPAD 1100
#define WST  1160   // guarded stride for conv-phase buffers: col = w + 2, zeros outside [0,1100)
#define NT   30
#define OC1  256
#define OC2  512
#define OC3  1024

typedef __attribute__((ext_vector_type(8))) short bf16x8;
typedef __attribute__((ext_vector_type(4))) float f32x4;
typedef unsigned short u16;
typedef unsigned int u32;

__device__ __forceinline__ u16 f2bf(float f){
  __hip_bfloat16 h = __float2bfloat16(f);
  u16 u; __builtin_memcpy(&u, &h, 2); return u;
}
__device__ __forceinline__ float bf2f(u16 u){
  __hip_bfloat16 h; __builtin_memcpy(&h, &u, 2); return __bfloat162float(h);
}

// ---------------- VLAD branch (fp32) ----------------

__global__ __launch_bounds__(256) void transpose_xt(const float* __restrict__ x, float* __restrict__ xt){
  __shared__ float tile[32][33];
  int n = blockIdx.z;
  int r0 = blockIdx.y*32, w0 = blockIdx.x*32;
  int t = threadIdx.x;
  int tr = t >> 5, tc = t & 31;
  #pragma unroll
  for (int i = 0; i < 4; ++i){
    int r = r0 + tr + i*8, w = w0 + tc;
    tile[tr + i*8][tc] = (w < WW) ? x[((size_t)n*(DIM*HH) + r)*WW + w] : 0.f;
  }
  __syncthreads();
  #pragma unroll
  for (int i = 0; i < 4; ++i){
    int w = w0 + tr + i*8, r = r0 + tc;
    if (w < WW) xt[((size_t)n*WW + w)*(DIM*HH) + r] = tile[tc][tr + i*8];
  }
}

__global__ __launch_bounds__(256) void vlad_softmax(const float* __restrict__ x,
    const float* __restrict__ conv_w, const float* __restrict__ conv_b, float* __restrict__ a){
  __shared__ float cwT[DIM*KC];
  __shared__ float cbs[KC];
  int t = threadIdx.x;
  for (int i = t; i < DIM*KC; i += 256){ int c = i >> 6, k = i & 63; cwT[i] = conv_w[k*DIM + c]; }
  if (t < KC) cbs[t] = conv_b[t];
  __syncthreads();
  int w = blockIdx.x*256 + t, h = blockIdx.y, n = blockIdx.z;
  bool ok = (w < WW);
  float lg[KC];
  #pragma unroll
  for (int k = 0; k < KC; ++k) lg[k] = cbs[k];
  const float* xp = x + (size_t)n*DIM*HH*WW + (size_t)h*WW + (ok ? w : 0);
  for (int c = 0; c < DIM; ++c){
    float xv = ok ? xp[(size_t)c*HH*WW] : 0.f;
    const float* cw = &cwT[c*KC];
    #pragma unroll
    for (int k = 0; k < KC; ++k) lg[k] += xv * cw[k];
  }
  float m = lg[0];
  #pragma unroll
  for (int k = 1; k < KC; ++k) m = fmaxf(m, lg[k]);
  float s = 0.f;
  #pragma unroll
  for (int k = 0; k < KC; ++k){ lg[k] = __expf(lg[k]-m); s += lg[k]; }
  float inv = 1.f/s;
  if (ok){
    float* dst = a + (((size_t)(n*HH + h))*WW + w)*KC;
    #pragma unroll
    for (int k = 0; k < KC; k += 4){
      float4 v = make_float4(lg[k]*inv, lg[k+1]*inv, lg[k+2]*inv, lg[k+3]*inv);
      *(float4*)&dst[k] = v;
    }
  }
}

// fused: per (n, segment s of 10 padded-w positions) accumulate
// ps[k][c] = sum_{w in seg} ( sum_h a[k,h,w]*x[c,h,w] ) - centers[k][c] * sum_{w in seg} sum_h a[k,h,w]
__global__ __launch_bounds__(256) void vlad_xa2(const float* __restrict__ xt, const float* __restrict__ a,
    const float* __restrict__ centers, float* __restrict__ ps){
  __shared__ float aT[HH][KC];
  __shared__ float xT[DIM*HH];
  int t = threadIdx.x, s = blockIdx.x, n = blockIdx.y;
  int k = t >> 2, cb4 = t & 3;
  float acc[32];
  #pragma unroll
  for (int j = 0; j < 32; ++j) acc[j] = 0.f;
  float Sacc = 0.f;
  for (int i = 0; i < 10; ++i){
    int p = s*10 + i;
    int w = (p < 100) ? p + 800 : ((p < 1000) ? p - 100 : p - 1000);
    for (int e = t; e < HH*KC; e += 256){
      int h = e >> 6, kk = e & 63;
      aT[h][kk] = a[(((size_t)(n*HH + h))*WW + w)*KC + kk];
    }
    {
      const float4* src = (const float4*)(xt + ((size_t)n*WW + w)*(DIM*HH));
      float4* dst4 = (float4*)xT;
      for (int e = t; e < (DIM*HH)/4; e += 256) dst4[e] = src[e];
    }
    __syncthreads();
    float areg[HH];
    #pragma unroll
    for (int h = 0; h < HH; ++h) areg[h] = aT[h][k];
    float Sw = 0.f;
    #pragma unroll
    for (int h = 0; h < HH; ++h) Sw += areg[h];
    Sacc += Sw;
    #pragma unroll 2
    for (int j = 0; j < 32; ++j){
      const float4* xr = (const float4*)&xT[(cb4 + 4*j)*HH];
      float sum = 0.f;
      #pragma unroll
      for (int h4 = 0; h4 < HH/4; ++h4){
        float4 xv = xr[h4];
        sum += areg[h4*4+0]*xv.x + areg[h4*4+1]*xv.y + areg[h4*4+2]*xv.z + areg[h4*4+3]*xv.w;
      }
      acc[j] += sum;
    }
    __syncthreads();
  }
  const float* ck = centers + (size_t)k*DIM;
  float* dst = ps + (((size_t)(n*KC + k))*110 + s)*DIM;
  #pragma unroll
  for (int j = 0; j < 32; ++j){
    int c = cb4 + 4*j;
    dst[c] = acc[j] - ck[c]*Sacc;
  }
}

// window tt = segments [3tt, 3tt+20); sum + intra (per-cluster) L2 norm
__global__ __launch_bounds__(128) void vlad_win2(const float* __restrict__ ps, float* __restrict__ vlad){
  int c = threadIdx.x, k = blockIdx.x, tt = blockIdx.y, n = blockIdx.z;
  const float* base = ps + ((size_t)(n*KC + k))*110*DIM + c;
  float v = 0.f;
  #pragma unroll
  for (int u = 0; u < 20; ++u) v += base[(3*tt + u)*DIM];
  float ss = v*v;
  #pragma unroll
  for (int m = 1; m < 64; m <<= 1) ss += __shfl_xor(ss, m);
  __shared__ float red[2];
  if ((c & 63) == 0) red[c >> 6] = ss;
  __syncthreads();
  float tot = red[0] + red[1];
  float inv = 1.f / fmaxf(sqrtf(tot), 1e-12f);
  vlad[(((size_t)(n*NT + tt))*KC + k)*DIM + c] = v*inv;
}

__global__ __launch_bounds__(256) void vlad_gnorm(float* __restrict__ vlad){
  int row = blockIdx.x, t = threadIdx.x;
  float4* v = (float4*)(vlad + (size_t)row*(KC*DIM));
  float4 r[8]; float ss = 0.f;
  #pragma unroll
  for (int i = 0; i < 8; ++i){
    r[i] = v[t + i*256];
    ss += r[i].x*r[i].x + r[i].y*r[i].y + r[i].z*r[i].z + r[i].w*r[i].w;
  }
  #pragma unroll
  for (int m = 1; m < 64; m <<= 1) ss += __shfl_xor(ss, m);
  __shared__ float red[4];
  if ((t & 63) == 0) red[t >> 6] = ss;
  __syncthreads();
  float tot = red[0]+red[1]+red[2]+red[3];
  float inv = 1.f / fmaxf(sqrtf(tot), 1e-12f);
  #pragma unroll
  for (int i = 0; i < 8; ++i){
    float4 o = r[i]; o.x*=inv; o.y*=inv; o.z*=inv; o.w*=inv;
    v[t + i*256] = o;
  }
}

// ---------------- conv tower (bf16 MFMA, NHWC, guarded stride WST) ----------------

__global__ __launch_bounds__(256) void build_xpb(const float* __restrict__ x, u16* __restrict__ xpb){
  __shared__ u16 tile[DIM][33];
  int t = threadIdx.x, h = blockIdx.y, n = blockIdx.z;
  int b0 = blockIdx.x*32;
  #pragma unroll
  for (int i = 0; i < 16; ++i){
    int e = t + i*256;
    int c = e >> 5, bl = e & 31;
    int b = b0 + bl, w = b - 2;
    float v = 0.f;
    if (w >= 0 && w < WPAD){
      int wsrc = (w + 800) % 900;
      v = x[((size_t)(n*DIM + c)*HH + h)*WW + wsrc];
    }
    tile[c][bl] = f2bf(v);
  }
  __syncthreads();
  #pragma unroll
  for (int i = 0; i < 16; ++i){
    int e = t + i*256;
    int bl = e >> 7, c = e & 127;
    int b = b0 + bl;
    if (b < WST) xpb[((size_t)(n*HH + h)*WST + b)*DIM + c] = tile[c][bl];
  }
}

__global__ __launch_bounds__(256) void pack_w(const float* __restrict__ w, u16* __restrict__ wp, int OC, int IC){
  int idx = blockIdx.x*256 + threadIdx.x;
  int total = OC*IC*25;
  if (idx >= total) return;
  int ic = idx % IC; int r = idx / IC; int oc = r % OC; int tap = r / OC;
  wp[idx] = f2bf(w[((size_t)oc*IC + ic)*25 + tap]);
}

// 5x5 conv pad 2. Block 128oc x 128w, 4 waves of 64x64. Single LDS buffers (66.5KB,
// 2 blocks/CU) + T14 register staging: next tap's weights (8 uint4/thread) and next
// (dh,icb) slab's input (9 uint4/thread) loaded a phase early, ds_written at phase head.
// Raw barriers with lgkmcnt-only waits; no vmcnt(0) drain anywhere in the loop.
// __launch_bounds__(256,2): 2 waves/EU -> 256-VGPR cap; the ~200-VGPR staging set
// must NOT spill (round-4 lesson: default bounds capped at 88 VGPR -> scratch 6 GB).
template<int IC, int OC, int H>
__global__ __launch_bounds__(256,2) void conv5x5(const u16* __restrict__ in, const u16* __restrict__ wp,
    const float* __restrict__ bias, u16* __restrict__ out){
  constexpr int NICB = IC/128;
  constexpr int LN = (NICB==1?0:(NICB==2?1:2));
  __shared__ u16 sW[128*128];    // 32 KB  [oc][ic] swizzled
  __shared__ u16 sIn[132*128];   // 33 KB  [w'][ic] swizzled
  int t = threadIdx.x;
  int wave = t >> 6, lane = t & 63, lr = lane & 15, lgp = lane >> 4;
  int w0  = blockIdx.x * 128;
  int ocb = blockIdx.y * 128;
  int nh = blockIdx.z; int n = nh / H, h = nh % H;
  int wo_oc = (wave & 1)*64, wo_w = (wave >> 1)*64;
  int dhlo = (2-h > 0) ? (2-h) : 0;
  int dhhi = (H+1-h < 4) ? (H+1-h) : 4;
  int nslab = (dhhi - dhlo + 1) << LN;
  int P = nslab * 5;
  const u16* inN = in + (size_t)n*H*WST*IC;

  // fixed per-thread chunk geometry (chunk q -> row r, swizzled col c = cp ^ (r&7))
  int wgOff[8], wlOff[8];
  #pragma unroll
  for (int j = 0; j < 8; ++j){
    int q = j*256 + t, r = q >> 4, cp = q & 15, c = cp ^ (r & 7);
    wgOff[j] = r*IC + c*8;
    wlOff[j] = q*8;
  }
  int igOff[9], ilOff[9];
  #pragma unroll
  for (int j = 0; j < 9; ++j){
    int q = j*256 + t;              // j==8 valid only for t<64 (rows 128..131)
    int r = q >> 4, cp = q & 15, c = cp ^ (r & 7);
    igOff[j] = (w0 + r)*IC + c*8;   // max col 1155 < WST
    ilOff[j] = q*8;
  }
  bool has9 = (t < 64);

  uint4 rw[8], ri[9];
  auto wtapbase = [&](int slab_, int dw_) -> const u16* {
    int dh = dhlo + (slab_ >> LN);
    int icb = slab_ & (NICB-1);
    return wp + ((size_t)(dh*5 + dw_)*OC + ocb)*IC + icb*128;
  };
  auto ibase_f = [&](int slab_) -> const u16* {
    int dh = dhlo + (slab_ >> LN);
    int icb = slab_ & (NICB-1);
    return inN + (size_t)(h + dh - 2)*WST*IC + icb*128;
  };
  {
    const u16* wb = wtapbase(0, 0);
    #pragma unroll
    for (int j = 0; j < 8; ++j) rw[j] = *(const uint4*)(wb + wgOff[j]);
    const u16* ib = ibase_f(0);
    #pragma unroll
    for (int j = 0; j < 8; ++j) ri[j] = *(const uint4*)(ib + igOff[j]);
    if (has9) ri[8] = *(const uint4*)(ib + igOff[8]);
  }

  f32x4 acc[4][4] = {};
  int slab = 0, dw = 0;
  for (int p = 0; p < P; ++p){
    __builtin_amdgcn_s_barrier();          // all waves done reading LDS of prev phase
    __builtin_amdgcn_sched_barrier(0);
    #pragma unroll
    for (int j = 0; j < 8; ++j) *(uint4*)&sW[wlOff[j]] = rw[j];
    if (dw == 0){
      #pragma unroll
      for (int j = 0; j < 8; ++j) *(uint4*)&sIn[ilOff[j]] = ri[j];
      if (has9) *(uint4*)&sIn[ilOff[8]] = ri[8];
    }
    if (p + 1 < P){
      int dwn = dw + 1, sn = slab;
      if (dwn == 5){ dwn = 0; sn = slab + 1; }
      const u16* wb = wtapbase(sn, dwn);
      #pragma unroll
      for (int j = 0; j < 8; ++j) rw[j] = *(const uint4*)(wb + wgOff[j]);
    }
    if (dw == 3 && slab + 1 < nslab){
      const u16* ib = ibase_f(slab + 1);
      #pragma unroll
      for (int j = 0; j < 8; ++j) ri[j] = *(const uint4*)(ib + igOff[j]);
      if (has9) ri[8] = *(const uint4*)(ib + igOff[8]);
    }
    __builtin_amdgcn_sched_barrier(0);
    asm volatile("s_waitcnt lgkmcnt(0)" ::: "memory");   // my ds_writes complete
    __builtin_amdgcn_s_barrier();                        // everyone's writes complete
    __builtin_amdgcn_sched_barrier(0);
    __builtin_amdgcn_s_setprio(1);
    #pragma unroll
    for (int k0i = 0; k0i < 4; ++k0i){
      bf16x8 A[4], B[4];
      #pragma unroll
      for (int j = 0; j < 4; ++j){
        int ar = wo_oc + j*16 + lr;
        A[j] = *(const bf16x8*)&sW[ar*128 + (((k0i*4 + lgp) ^ (lr & 7)) << 3)];
        int br = wo_w + j*16 + lr + dw;
        B[j] = *(const bf16x8*)&sIn[br*128 + (((k0i*4 + lgp) ^ (br & 7)) << 3)];
      }
      #pragma unroll
      for (int ja = 0; ja < 4; ++ja)
        #pragma unroll
        for (int jb = 0; jb < 4; ++jb)
          acc[ja][jb] = __builtin_amdgcn_mfma_f32_16x16x32_bf16(A[ja], B[jb], acc[ja][jb], 0, 0, 0);
    }
    __builtin_amdgcn_s_setprio(0);
    __builtin_amdgcn_sched_barrier(0);
    ++dw; if (dw == 5){ dw = 0; ++slab; }
  }
  const size_t obase = ((size_t)(n*H + h)*WST + 2)*OC;
  #pragma unroll
  for (int ja = 0; ja < 4; ++ja){
    int oc = ocb + wo_oc + ja*16 + lgp*4;
    float4 bv = *(const float4*)&bias[oc];
    #pragma unroll
    for (int jb = 0; jb < 4; ++jb){
      int wg = w0 + wo_w + jb*16 + lr;
      if (wg < WPAD){
        f32x4 av = acc[ja][jb];
        ushort4 o;
        o.x = f2bf(av[0] + bv.x);
        o.y = f2bf(av[1] + bv.y);
        o.z = f2bf(av[2] + bv.z);
        o.w = f2bf(av[3] + bv.w);
        *(ushort4*)(out + obase + (size_t)wg*OC + oc) = o;
      }
    }
  }
}

// leaky(0.2) + maxpool 3x3 stride(3,1); 4 oc/thread (8B loads); writes full guarded range
__global__ __launch_bounds__(256) void pool1k(const u16* __restrict__ in, u16* __restrict__ out){
  int t = threadIdx.x;
  int wb = blockIdx.x*4 + (t >> 6);
  int oc = (t & 63)*4;
  int ho = blockIdx.y, n = blockIdx.z;
  int wo = wb - 2;
  float m0=0.f,m1=0.f,m2=0.f,m3=0.f;
  if (wo >= 0 && wo < WPAD){
    m0=m1=m2=m3=-1e30f;
    #pragma unroll
    for (int kh = 0; kh < 3; ++kh){
      const u16* row = in + ((size_t)(n*HH + ho*3 + kh)*WST + 2)*OC1 + oc;
      #pragma unroll
      for (int kw = 0; kw < 3; ++kw){
        int wi = wo - 1 + kw;
        if (wi >= 0 && wi < WPAD){
          ushort4 v = *(const ushort4*)(row + (size_t)wi*OC1);
          m0 = fmaxf(m0, bf2f(v.x)); m1 = fmaxf(m1, bf2f(v.y));
          m2 = fmaxf(m2, bf2f(v.z)); m3 = fmaxf(m3, bf2f(v.w));
        }
      }
    }
    m0 = (m0>0.f)?m0:0.2f*m0; m1 = (m1>0.f)?m1:0.2f*m1;
    m2 = (m2>0.f)?m2:0.2f*m2; m3 = (m3>0.f)?m3:0.2f*m3;
  }
  ushort4 o; o.x=f2bf(m0); o.y=f2bf(m1); o.z=f2bf(m2); o.w=f2bf(m3);
  *(ushort4*)(out + ((size_t)(n*16 + ho)*WST + wb)*OC1 + oc) = o;
}

// leaky(0.2) + maxpool 4x5 stride(4,1); 4 oc/thread
__global__ __launch_bounds__(256) void pool2k(const u16* __restrict__ in, u16* __restrict__ out){
  int t = threadIdx.x;
  int wb = blockIdx.x*2 + (t >> 7);
  int oc = (t & 127)*4;
  int ho = blockIdx.y, n = blockIdx.z;
  int wo = wb - 2;
  float m0=0.f,m1=0.f,m2=0.f,m3=0.f;
  if (wo >= 0 && wo < WPAD){
    m0=m1=m2=m3=-1e30f;
    #pragma unroll
    for (int kh = 0; kh < 4; ++kh){
      const u16* row = in + ((size_t)(n*16 + ho*4 + kh)*WST + 2)*OC2 + oc;
      #pragma unroll
      for (int kw = 0; kw < 5; ++kw){
        int wi = wo - 2 + kw;
        if (wi >= 0 && wi < WPAD){
          ushort4 v = *(const ushort4*)(row + (size_t)wi*OC2);
          m0 = fmaxf(m0, bf2f(v.x)); m1 = fmaxf(m1, bf2f(v.y));
          m2 = fmaxf(m2, bf2f(v.z)); m3 = fmaxf(m3, bf2f(v.w));
        }
      }
    }
    m0 = (m0>0.f)?m0:0.2f*m0; m1 = (m1>0.f)?m1:0.2f*m1;
    m2 = (m2>0.f)?m2:0.2f*m2; m3 = (m3>0.f)?m3:0.2f*m3;
  }
  ushort4 o; o.x=f2bf(m0); o.y=f2bf(m1); o.z=f2bf(m2); o.w=f2bf(m3);
  *(ushort4*)(out + ((size_t)(n*4 + ho)*WST + wb)*OC2 + oc) = o;
}

// maxpool 1x200 over one h-row, sampled every 30; partials per h -> xfraw [n][t][4][1024]
__global__ __launch_bounds__(256) void pool3k(const u16* __restrict__ in, float* __restrict__ xfraw){
  int tt = blockIdx.x, hh = blockIdx.y, n = blockIdx.z;
  int oc = threadIdx.x*4;
  float m0=-1e30f,m1=-1e30f,m2=-1e30f,m3=-1e30f;
  const u16* row = in + ((size_t)(n*4 + hh)*WST + 2 + 30*tt)*OC3 + oc;
  for (int p = 0; p < 200; ++p){
    ushort4 v = *(const ushort4*)(row + (size_t)p*OC3);
    m0 = fmaxf(m0, bf2f(v.x)); m1 = fmaxf(m1, bf2f(v.y));
    m2 = fmaxf(m2, bf2f(v.z)); m3 = fmaxf(m3, bf2f(v.w));
  }
  float* dst = xfraw + (((size_t)(n*NT + tt))*4 + hh)*OC3 + oc;
  dst[0]=m0; dst[1]=m1; dst[2]=m2; dst[3]=m3;
}

// combine 4 h-partials, L2 normalize -> xf [row][1024]
__global__ __launch_bounds__(256) void xf_norm(const float* __restrict__ xfraw, float* __restrict__ xf){
  int row = blockIdx.x, t = threadIdx.x;
  const float* src = xfraw + (size_t)row*4096;
  float v[4]; float ss = 0.f;
  #pragma unroll
  for (int j = 0; j < 4; ++j){
    float m = src[t + j*256];
    #pragma unroll
    for (int hh = 1; hh < 4; ++hh) m = fmaxf(m, src[hh*1024 + t + j*256]);
    v[j] = m; ss += m*m;
  }
  #pragma unroll
  for (int m = 1; m < 64; m <<= 1) ss += __shfl_xor(ss, m);
  __shared__ float red[4];
  if ((t & 63) == 0) red[t >> 6] = ss;
  __syncthreads();
  float tot = red[0]+red[1]+red[2]+red[3];
  float inv = 1.f/fmaxf(sqrtf(tot), 1e-12f);
  float* dst = xf + (size_t)row*OC3;
  #pragma unroll
  for (int j = 0; j < 4; ++j) dst[t + j*256] = v[j]*inv;
}

__global__ __launch_bounds__(256) void final_mlp(const float* __restrict__ vlad, const float* __restrict__ xf,
    const float* __restrict__ W, const float* __restrict__ b, float* __restrict__ out){
  __shared__ float feat[9216];
  __shared__ float red[4];
  int row = blockIdx.x, t = threadIdx.x;
  {
    const float4* v = (const float4*)(vlad + (size_t)row*8192);
    float4* f4 = (float4*)feat;
    for (int i = t; i < 2048; i += 256) f4[i] = v[i];
    const float4* xv = (const float4*)(xf + (size_t)row*1024);
    if (t < 256) f4[2048 + t] = xv[t];
  }
  __syncthreads();
  const float* wr = W + (size_t)t*9216;
  float acc = b[t];
  for (int i = 0; i < 9216; i += 4){
    float4 wv = *(const float4*)&wr[i];
    acc += feat[i]*wv.x + feat[i+1]*wv.y + feat[i+2]*wv.z + feat[i+3]*wv.w;
  }
  float ss = acc*acc;
  #pragma unroll
  for (int m = 1; m < 64; m <<= 1) ss += __shfl_xor(ss, m);
  if ((t & 63) == 0) red[t >> 6] = ss;
  __syncthreads();
  float tot = red[0]+red[1]+red[2]+red[3];
  float inv = 1.f/fmaxf(sqrtf(tot), 1e-12f);
  out[(size_t)row*256 + t] = acc*inv;
}

// ---------------- launch ----------------
extern "C" void kernel_launch(void* const* d_in, const int* in_sizes, int n_in,
                              void* d_out, int out_size, void* d_ws, size_t ws_size,
                              hipStream_t stream){
  const float* x       = (const float*)d_in[0];
  const float* centers = (const float*)d_in[1];
  const float* conv_w  = (const float*)d_in[2];
  const float* conv_b  = (const float*)d_in[3];
  const float* w1      = (const float*)d_in[4];
  const float* b1      = (const float*)d_in[5];
  const float* w2      = (const float*)d_in[6];
  const float* b2      = (const float*)d_in[7];
  const float* w3      = (const float*)d_in[8];
  const float* b3      = (const float*)d_in[9];
  const float* mlp_w   = (const float*)d_in[10];
  const float* mlp_b   = (const float*)d_in[11];
  float* out = (float*)d_out;
  char* ws = (char*)d_ws;
  const size_t MB = 1ull << 20;
  if (ws_size < 248*MB) return;

  // persistent small buffers
  float* vlad  = (float*)(ws + 0);        // 3.75 MiB
  float* xf    = (float*)(ws + 4*MB);     // 0.47 MiB
  float* xfraw = (float*)(ws + 5*MB);     // 1.97 MiB
  char*  AR    = ws + 7*MB;               // arena (241 MiB), phase-reused
  // VLAD phase
  float* xt = (float*)(AR + 0);           // 84.4 MiB
  float* a  = (float*)(AR + 85*MB);       // 42.2 MiB (dead after vlad_xa2)
  float* ps = (float*)(AR + 128*MB);      // 14.4 MiB (dead after vlad_win2)
  // conv phase (after vlad_win2; regions recycled, stream-ordered)
  u16* xpb = (u16*)(AR + 0);              // 54.4 MiB (over xt)
  u16* wp1 = (u16*)(AR + 55*MB);          // 1.6 MiB
  u16* wp2 = (u16*)(AR + 57*MB);          // 6.25 MiB
  u16* wp3 = (u16*)(AR + 64*MB);          // 25 MiB
  u16* h1  = (u16*)(AR + 89*MB);          // 108.75 MiB (over a/ps)
  u16* p1  = (u16*)(AR + 0);              // 36.25 MiB (over xpb, dead after conv1)
  u16* h2  = (u16*)(AR + 89*MB);          // 72.5 MiB (over h1, dead after pool1)
  u16* p2  = (u16*)(AR + 163*MB);         // 18.1 MiB (past h2)
  u16* h3  = (u16*)(AR + 0);              // 36.25 MiB (over p1, dead after conv2)

  // ---- VLAD (fp32) ----
  transpose_xt<<<dim3(29,192,NB), 256, 0, stream>>>(x, xt);
  vlad_softmax<<<dim3(4,HH,NB), 256, 0, stream>>>(x, conv_w, conv_b, a);
  vlad_xa2<<<dim3(110,NB), 256, 0, stream>>>(xt, a, centers, ps);
  vlad_win2<<<dim3(KC,NT,NB), 128, 0, stream>>>(ps, vlad);
  vlad_gnorm<<<dim3(NB*NT), 256, 0, stream>>>(vlad);

  // ---- conv tower (bf16 MFMA) ----
  pack_w<<<dim3(3200),  256, 0, stream>>>(w1, wp1, OC1, DIM);
  pack_w<<<dim3(12800), 256, 0, stream>>>(w2, wp2, OC2, OC1);
  pack_w<<<dim3(51200), 256, 0, stream>>>(w3, wp3, OC3, OC2);
  build_xpb<<<dim3(37,HH,NB), 256, 0, stream>>>(x, xpb);
  conv5x5<128,256,48><<<dim3(9, OC1/128, NB*HH), 256, 0, stream>>>(xpb, wp1, b1, h1);
  pool1k<<<dim3(WST/4,16,NB), 256, 0, stream>>>(h1, p1);
  conv5x5<256,512,16><<<dim3(9, OC2/128, NB*16), 256, 0, stream>>>(p1, wp2, b2, h2);
  pool2k<<<dim3(WST/2,4,NB), 256, 0, stream>>>(h2, p2);
  conv5x5<512,1024,4><<<dim3(9, OC3/128, NB*4), 256, 0, stream>>>(p2, wp3, b3, h3);
  pool3k<<<dim3(NT,4,NB), 256, 0, stream>>>(h3, xfraw);
  xf_norm<<<dim3(NB*NT), 256, 0, stream>>>(xfraw, xf);

  // ---- head ----
  final_mlp<<<dim3(NB*NT), 256, 0, stream>>>(vlad, xf, mlp_w, mlp_b, out);
}

// Round 6
// 2388.898 us; speedup vs baseline: 1.8140x; 1.8140x over previous
//
#include <hip/hip_runtime.h>
#include <hip/hip_bf16.h>

// ---------------- constants ----------------
#define NB   4
#define DIM  128
#define KC   64
#define HH   48
#define WW   900
#define WPAD 1100
#define WST  1160   // guarded stride for conv-phase buffers: col = w + 2, zeros outside [0,1100)
#define NT   30
#define OC1  256
#define OC2  512
#define OC3  1024

typedef __attribute__((ext_vector_type(8))) short bf16x8;
typedef __attribute__((ext_vector_type(4))) float f32x4;
typedef unsigned short u16;
typedef unsigned int u32;

__device__ __forceinline__ u16 f2bf(float f){
  __hip_bfloat16 h = __float2bfloat16(f);
  u16 u; __builtin_memcpy(&u, &h, 2); return u;
}
__device__ __forceinline__ float bf2f(u16 u){
  __hip_bfloat16 h; __builtin_memcpy(&h, &u, 2); return __bfloat162float(h);
}

typedef __attribute__((address_space(1))) const u32 g_u32;
typedef __attribute__((address_space(3))) u32 l_u32;
// async global->LDS, 16B per lane; LDS dest = uniform base + lane*16
__device__ __forceinline__ void gll16(const void* g, void* l){
  __builtin_amdgcn_global_load_lds((g_u32*)g, (l_u32*)l, 16, 0, 0);
}

// ---------------- VLAD branch (fp32) ----------------

__global__ __launch_bounds__(256) void transpose_xt(const float* __restrict__ x, float* __restrict__ xt){
  __shared__ float tile[32][33];
  int n = blockIdx.z;
  int r0 = blockIdx.y*32, w0 = blockIdx.x*32;
  int t = threadIdx.x;
  int tr = t >> 5, tc = t & 31;
  #pragma unroll
  for (int i = 0; i < 4; ++i){
    int r = r0 + tr + i*8, w = w0 + tc;
    tile[tr + i*8][tc] = (w < WW) ? x[((size_t)n*(DIM*HH) + r)*WW + w] : 0.f;
  }
  __syncthreads();
  #pragma unroll
  for (int i = 0; i < 4; ++i){
    int w = w0 + tr + i*8, r = r0 + tc;
    if (w < WW) xt[((size_t)n*WW + w)*(DIM*HH) + r] = tile[tc][tr + i*8];
  }
}

__global__ __launch_bounds__(256) void vlad_softmax(const float* __restrict__ x,
    const float* __restrict__ conv_w, const float* __restrict__ conv_b, float* __restrict__ a){
  __shared__ float cwT[DIM*KC];
  __shared__ float cbs[KC];
  int t = threadIdx.x;
  for (int i = t; i < DIM*KC; i += 256){ int c = i >> 6, k = i & 63; cwT[i] = conv_w[k*DIM + c]; }
  if (t < KC) cbs[t] = conv_b[t];
  __syncthreads();
  int w = blockIdx.x*256 + t, h = blockIdx.y, n = blockIdx.z;
  bool ok = (w < WW);
  float lg[KC];
  #pragma unroll
  for (int k = 0; k < KC; ++k) lg[k] = cbs[k];
  const float* xp = x + (size_t)n*DIM*HH*WW + (size_t)h*WW + (ok ? w : 0);
  for (int c = 0; c < DIM; ++c){
    float xv = ok ? xp[(size_t)c*HH*WW] : 0.f;
    const float* cw = &cwT[c*KC];
    #pragma unroll
    for (int k = 0; k < KC; ++k) lg[k] += xv * cw[k];
  }
  float m = lg[0];
  #pragma unroll
  for (int k = 1; k < KC; ++k) m = fmaxf(m, lg[k]);
  float s = 0.f;
  #pragma unroll
  for (int k = 0; k < KC; ++k){ lg[k] = __expf(lg[k]-m); s += lg[k]; }
  float inv = 1.f/s;
  if (ok){
    float* dst = a + (((size_t)(n*HH + h))*WW + w)*KC;
    #pragma unroll
    for (int k = 0; k < KC; k += 4){
      float4 v = make_float4(lg[k]*inv, lg[k+1]*inv, lg[k+2]*inv, lg[k+3]*inv);
      *(float4*)&dst[k] = v;
    }
  }
}

// fused: per (n, segment s of 10 padded-w positions) accumulate
// ps[k][c] = sum_{w in seg} ( sum_h a[k,h,w]*x[c,h,w] ) - centers[k][c] * sum_{w in seg} sum_h a[k,h,w]
__global__ __launch_bounds__(256) void vlad_xa2(const float* __restrict__ xt, const float* __restrict__ a,
    const float* __restrict__ centers, float* __restrict__ ps){
  __shared__ float aT[HH][KC];
  __shared__ float xT[DIM*HH];
  int t = threadIdx.x, s = blockIdx.x, n = blockIdx.y;
  int k = t >> 2, cb4 = t & 3;
  float acc[32];
  #pragma unroll
  for (int j = 0; j < 32; ++j) acc[j] = 0.f;
  float Sacc = 0.f;
  for (int i = 0; i < 10; ++i){
    int p = s*10 + i;
    int w = (p < 100) ? p + 800 : ((p < 1000) ? p - 100 : p - 1000);
    for (int e = t; e < HH*KC; e += 256){
      int h = e >> 6, kk = e & 63;
      aT[h][kk] = a[(((size_t)(n*HH + h))*WW + w)*KC + kk];
    }
    {
      const float4* src = (const float4*)(xt + ((size_t)n*WW + w)*(DIM*HH));
      float4* dst4 = (float4*)xT;
      for (int e = t; e < (DIM*HH)/4; e += 256) dst4[e] = src[e];
    }
    __syncthreads();
    float areg[HH];
    #pragma unroll
    for (int h = 0; h < HH; ++h) areg[h] = aT[h][k];
    float Sw = 0.f;
    #pragma unroll
    for (int h = 0; h < HH; ++h) Sw += areg[h];
    Sacc += Sw;
    #pragma unroll 2
    for (int j = 0; j < 32; ++j){
      const float4* xr = (const float4*)&xT[(cb4 + 4*j)*HH];
      float sum = 0.f;
      #pragma unroll
      for (int h4 = 0; h4 < HH/4; ++h4){
        float4 xv = xr[h4];
        sum += areg[h4*4+0]*xv.x + areg[h4*4+1]*xv.y + areg[h4*4+2]*xv.z + areg[h4*4+3]*xv.w;
      }
      acc[j] += sum;
    }
    __syncthreads();
  }
  const float* ck = centers + (size_t)k*DIM;
  float* dst = ps + (((size_t)(n*KC + k))*110 + s)*DIM;
  #pragma unroll
  for (int j = 0; j < 32; ++j){
    int c = cb4 + 4*j;
    dst[c] = acc[j] - ck[c]*Sacc;
  }
}

// window tt = segments [3tt, 3tt+20); sum + intra (per-cluster) L2 norm
__global__ __launch_bounds__(128) void vlad_win2(const float* __restrict__ ps, float* __restrict__ vlad){
  int c = threadIdx.x, k = blockIdx.x, tt = blockIdx.y, n = blockIdx.z;
  const float* base = ps + ((size_t)(n*KC + k))*110*DIM + c;
  float v = 0.f;
  #pragma unroll
  for (int u = 0; u < 20; ++u) v += base[(3*tt + u)*DIM];
  float ss = v*v;
  #pragma unroll
  for (int m = 1; m < 64; m <<= 1) ss += __shfl_xor(ss, m);
  __shared__ float red[2];
  if ((c & 63) == 0) red[c >> 6] = ss;
  __syncthreads();
  float tot = red[0] + red[1];
  float inv = 1.f / fmaxf(sqrtf(tot), 1e-12f);
  vlad[(((size_t)(n*NT + tt))*KC + k)*DIM + c] = v*inv;
}

__global__ __launch_bounds__(256) void vlad_gnorm(float* __restrict__ vlad){
  int row = blockIdx.x, t = threadIdx.x;
  float4* v = (float4*)(vlad + (size_t)row*(KC*DIM));
  float4 r[8]; float ss = 0.f;
  #pragma unroll
  for (int i = 0; i < 8; ++i){
    r[i] = v[t + i*256];
    ss += r[i].x*r[i].x + r[i].y*r[i].y + r[i].z*r[i].z + r[i].w*r[i].w;
  }
  #pragma unroll
  for (int m = 1; m < 64; m <<= 1) ss += __shfl_xor(ss, m);
  __shared__ float red[4];
  if ((t & 63) == 0) red[t >> 6] = ss;
  __syncthreads();
  float tot = red[0]+red[1]+red[2]+red[3];
  float inv = 1.f / fmaxf(sqrtf(tot), 1e-12f);
  #pragma unroll
  for (int i = 0; i < 8; ++i){
    float4 o = r[i]; o.x*=inv; o.y*=inv; o.z*=inv; o.w*=inv;
    v[t + i*256] = o;
  }
}

// ---------------- conv tower (bf16 MFMA, NHWC, guarded stride WST) ----------------

__global__ __launch_bounds__(256) void build_xpb(const float* __restrict__ x, u16* __restrict__ xpb){
  __shared__ u16 tile[DIM][33];
  int t = threadIdx.x, h = blockIdx.y, n = blockIdx.z;
  int b0 = blockIdx.x*32;
  #pragma unroll
  for (int i = 0; i < 16; ++i){
    int e = t + i*256;
    int c = e >> 5, bl = e & 31;
    int b = b0 + bl, w = b - 2;
    float v = 0.f;
    if (w >= 0 && w < WPAD){
      int wsrc = (w + 800) % 900;
      v = x[((size_t)(n*DIM + c)*HH + h)*WW + wsrc];
    }
    tile[c][bl] = f2bf(v);
  }
  __syncthreads();
  #pragma unroll
  for (int i = 0; i < 16; ++i){
    int e = t + i*256;
    int bl = e >> 7, c = e & 127;
    int b = b0 + bl;
    if (b < WST) xpb[((size_t)(n*HH + h)*WST + b)*DIM + c] = tile[c][bl];
  }
}

__global__ __launch_bounds__(256) void pack_w(const float* __restrict__ w, u16* __restrict__ wp, int OC, int IC){
  int idx = blockIdx.x*256 + threadIdx.x;
  int total = OC*IC*25;
  if (idx >= total) return;
  int ic = idx % IC; int r = idx / IC; int oc = r % OC; int tap = r / OC;
  wp[idx] = f2bf(w[((size_t)oc*IC + ic)*25 + tap]);
}

// 5x5 conv pad 2. Block = 128oc x 128w x 2 output h-rows, 512 threads, 8 waves of
// 64oc x 64w x 1h. Weights: sW double-buffered (2x32KB), gll16-prefetched one tap
// ahead, counted s_waitcnt vmcnt(4) (never 0 inside the loop). Input: sIn ring-2 of
// h-rows (row h+dh-2 and h+dh-1 alternate slots); one new 33KB row staged per dh
// step (two per icb step); rows outside [0,H) are ds_write-zeroed. No register
// staging (round 4/5 lesson: compiler spills conditionally-redefined reg arrays).
template<int IC, int OC, int H>
__global__ __launch_bounds__(512,2) void conv5x5(const u16* __restrict__ in, const u16* __restrict__ wp,
    const float* __restrict__ bias, u16* __restrict__ out){
  constexpr int NICB = IC/128;
  __shared__ u16 sW[2*128*128];    // 64 KB, [buf][oc][ic] chunk-swizzled
  __shared__ u16 sIn[2*132*128];   // 66 KB, [slot][w'][ic] chunk-swizzled
  int t = threadIdx.x;
  int wave = t >> 6, lane = t & 63, lr = lane & 15, lgp = lane >> 4;
  int w0  = blockIdx.x * 128;
  int ocb = blockIdx.y * 128;
  int nh = blockIdx.z; int n = nh / (H/2), hp = nh % (H/2);
  int h = hp*2;
  int wo_oc = (wave & 1)*64, wo_w = ((wave >> 1) & 1)*64, jw = wave >> 2;  // jw = output row offset
  const u16* inN = in + (size_t)n*H*WST*IC;
  const int P = NICB*25;

  // stage one input h-row (idx in 0..5 => global row h-2+idx) into slot idx&1
  auto stage_row = [&](int idx, int icb_){
    int r = h - 2 + idx;
    u16* dstBase = &sIn[(idx & 1)*(132*128)];
    if (r >= 0 && r < H){
      const u16* src = inN + (size_t)r*WST*IC + (size_t)icb_*128;
      #pragma unroll
      for (int j = 0; j < 4; ++j){
        int q = j*512 + t; int rr = q >> 4, cp = q & 15, cc = cp ^ (rr & 7);
        gll16(src + (size_t)(w0 + rr)*IC + cc*8, dstBase + q*8);
      }
      if (t < 64){
        int q = 2048 + t; int rr = q >> 4, cp = q & 15, cc = cp ^ (rr & 7);
        gll16(src + (size_t)(w0 + rr)*IC + cc*8, dstBase + q*8);
      }
    } else {
      uint4 z = make_uint4(0,0,0,0);
      #pragma unroll
      for (int j = 0; j < 4; ++j) *(uint4*)&dstBase[(j*512 + t)*8] = z;
      if (t < 64) *(uint4*)&dstBase[(2048 + t)*8] = z;
    }
  };
  auto stage_w = [&](int icb_, int dh_, int dw_, int buf){
    const u16* src = wp + ((size_t)(dh_*5 + dw_)*OC + ocb)*IC + (size_t)icb_*128;
    u16* dstBase = &sW[buf*(128*128)];
    #pragma unroll
    for (int j = 0; j < 4; ++j){
      int q = j*512 + t; int rr = q >> 4, cp = q & 15, cc = cp ^ (rr & 7);
      gll16(src + (size_t)rr*IC + cc*8, dstBase + q*8);
    }
  };

  // prologue: rows idx 0,1 for icb=0; weights tap (0,0) icb=0 into buf 0
  stage_row(0, 0);
  stage_row(1, 0);
  stage_w(0, 0, 0, 0);

  f32x4 acc[4][4] = {};
  int icb = 0, dh = 0, dw = 0;
  for (int p = 0; p < P; ++p){
    // ring advance at group entry (slot's last reader was phase p-1; barrier passed)
    if (dw == 0 && p > 0){
      if (dh == 0){ stage_row(0, icb); stage_row(1, icb); }
      else        { stage_row(dh + 1, icb); }
    }
    bool more = (p + 1 < P);
    if (more){
      int dwn = dw + 1, dhn = dh, icn = icb;
      if (dwn == 5){ dwn = 0; ++dhn; if (dhn == 5){ dhn = 0; ++icn; } }
      stage_w(icn, dhn, dwn, (p + 1) & 1);
    }
    if (more) asm volatile("s_waitcnt vmcnt(4) lgkmcnt(0)" ::: "memory");
    else      asm volatile("s_waitcnt vmcnt(0) lgkmcnt(0)" ::: "memory");
    __builtin_amdgcn_s_barrier();
    __builtin_amdgcn_sched_barrier(0);
    const u16* sWp = &sW[(p & 1)*(128*128)];
    const u16* sBp = &sIn[((dh + jw) & 1)*(132*128)];
    #pragma unroll
    for (int k0i = 0; k0i < 4; ++k0i){
      bf16x8 A[4], B[4];
      #pragma unroll
      for (int j = 0; j < 4; ++j){
        int ar = wo_oc + j*16 + lr;
        A[j] = *(const bf16x8*)&sWp[ar*128 + (((k0i*4 + lgp) ^ (lr & 7)) << 3)];
        int br = wo_w + j*16 + lr + dw;
        B[j] = *(const bf16x8*)&sBp[br*128 + (((k0i*4 + lgp) ^ (br & 7)) << 3)];
      }
      #pragma unroll
      for (int ja = 0; ja < 4; ++ja)
        #pragma unroll
        for (int jb = 0; jb < 4; ++jb)
          acc[ja][jb] = __builtin_amdgcn_mfma_f32_16x16x32_bf16(A[ja], B[jb], acc[ja][jb], 0, 0, 0);
    }
    __builtin_amdgcn_sched_barrier(0);
    __builtin_amdgcn_s_barrier();
    ++dw; if (dw == 5){ dw = 0; ++dh; if (dh == 5){ dh = 0; ++icb; } }
  }

  const size_t obase = ((size_t)(n*H + h + jw)*WST + 2)*OC;
  #pragma unroll
  for (int ja = 0; ja < 4; ++ja){
    int oc = ocb + wo_oc + ja*16 + lgp*4;
    float4 bv = *(const float4*)&bias[oc];
    #pragma unroll
    for (int jb = 0; jb < 4; ++jb){
      int wg = w0 + wo_w + jb*16 + lr;
      if (wg < WPAD){
        f32x4 av = acc[ja][jb];
        ushort4 o;
        o.x = f2bf(av[0] + bv.x);
        o.y = f2bf(av[1] + bv.y);
        o.z = f2bf(av[2] + bv.z);
        o.w = f2bf(av[3] + bv.w);
        *(ushort4*)(out + obase + (size_t)wg*OC + oc) = o;
      }
    }
  }
}

// leaky(0.2) + maxpool 3x3 stride(3,1); 4 oc/thread (8B loads); writes full guarded range
__global__ __launch_bounds__(256) void pool1k(const u16* __restrict__ in, u16* __restrict__ out){
  int t = threadIdx.x;
  int wb = blockIdx.x*4 + (t >> 6);
  int oc = (t & 63)*4;
  int ho = blockIdx.y, n = blockIdx.z;
  int wo = wb - 2;
  float m0=0.f,m1=0.f,m2=0.f,m3=0.f;
  if (wo >= 0 && wo < WPAD){
    m0=m1=m2=m3=-1e30f;
    #pragma unroll
    for (int kh = 0; kh < 3; ++kh){
      const u16* row = in + ((size_t)(n*HH + ho*3 + kh)*WST + 2)*OC1 + oc;
      #pragma unroll
      for (int kw = 0; kw < 3; ++kw){
        int wi = wo - 1 + kw;
        if (wi >= 0 && wi < WPAD){
          ushort4 v = *(const ushort4*)(row + (size_t)wi*OC1);
          m0 = fmaxf(m0, bf2f(v.x)); m1 = fmaxf(m1, bf2f(v.y));
          m2 = fmaxf(m2, bf2f(v.z)); m3 = fmaxf(m3, bf2f(v.w));
        }
      }
    }
    m0 = (m0>0.f)?m0:0.2f*m0; m1 = (m1>0.f)?m1:0.2f*m1;
    m2 = (m2>0.f)?m2:0.2f*m2; m3 = (m3>0.f)?m3:0.2f*m3;
  }
  ushort4 o; o.x=f2bf(m0); o.y=f2bf(m1); o.z=f2bf(m2); o.w=f2bf(m3);
  *(ushort4*)(out + ((size_t)(n*16 + ho)*WST + wb)*OC1 + oc) = o;
}

// leaky(0.2) + maxpool 4x5 stride(4,1); 4 oc/thread
__global__ __launch_bounds__(256) void pool2k(const u16* __restrict__ in, u16* __restrict__ out){
  int t = threadIdx.x;
  int wb = blockIdx.x*2 + (t >> 7);
  int oc = (t & 127)*4;
  int ho = blockIdx.y, n = blockIdx.z;
  int wo = wb - 2;
  float m0=0.f,m1=0.f,m2=0.f,m3=0.f;
  if (wo >= 0 && wo < WPAD){
    m0=m1=m2=m3=-1e30f;
    #pragma unroll
    for (int kh = 0; kh < 4; ++kh){
      const u16* row = in + ((size_t)(n*16 + ho*4 + kh)*WST + 2)*OC2 + oc;
      #pragma unroll
      for (int kw = 0; kw < 5; ++kw){
        int wi = wo - 2 + kw;
        if (wi >= 0 && wi < WPAD){
          ushort4 v = *(const ushort4*)(row + (size_t)wi*OC2);
          m0 = fmaxf(m0, bf2f(v.x)); m1 = fmaxf(m1, bf2f(v.y));
          m2 = fmaxf(m2, bf2f(v.z)); m3 = fmaxf(m3, bf2f(v.w));
        }
      }
    }
    m0 = (m0>0.f)?m0:0.2f*m0; m1 = (m1>0.f)?m1:0.2f*m1;
    m2 = (m2>0.f)?m2:0.2f*m2; m3 = (m3>0.f)?m3:0.2f*m3;
  }
  ushort4 o; o.x=f2bf(m0); o.y=f2bf(m1); o.z=f2bf(m2); o.w=f2bf(m3);
  *(ushort4*)(out + ((size_t)(n*4 + ho)*WST + wb)*OC2 + oc) = o;
}

// maxpool 1x200 over one h-row, sampled every 30; partials per h -> xfraw [n][t][4][1024]
__global__ __launch_bounds__(256) void pool3k(const u16* __restrict__ in, float* __restrict__ xfraw){
  int tt = blockIdx.x, hh = blockIdx.y, n = blockIdx.z;
  int oc = threadIdx.x*4;
  float m0=-1e30f,m1=-1e30f,m2=-1e30f,m3=-1e30f;
  const u16* row = in + ((size_t)(n*4 + hh)*WST + 2 + 30*tt)*OC3 + oc;
  for (int p = 0; p < 200; ++p){
    ushort4 v = *(const ushort4*)(row + (size_t)p*OC3);
    m0 = fmaxf(m0, bf2f(v.x)); m1 = fmaxf(m1, bf2f(v.y));
    m2 = fmaxf(m2, bf2f(v.z)); m3 = fmaxf(m3, bf2f(v.w));
  }
  float* dst = xfraw + (((size_t)(n*NT + tt))*4 + hh)*OC3 + oc;
  dst[0]=m0; dst[1]=m1; dst[2]=m2; dst[3]=m3;
}

// combine 4 h-partials, L2 normalize -> xf [row][1024]
__global__ __launch_bounds__(256) void xf_norm(const float* __restrict__ xfraw, float* __restrict__ xf){
  int row = blockIdx.x, t = threadIdx.x;
  const float* src = xfraw + (size_t)row*4096;
  float v[4]; float ss = 0.f;
  #pragma unroll
  for (int j = 0; j < 4; ++j){
    float m = src[t + j*256];
    #pragma unroll
    for (int hh = 1; hh < 4; ++hh) m = fmaxf(m, src[hh*1024 + t + j*256]);
    v[j] = m; ss += m*m;
  }
  #pragma unroll
  for (int m = 1; m < 64; m <<= 1) ss += __shfl_xor(ss, m);
  __shared__ float red[4];
  if ((t & 63) == 0) red[t >> 6] = ss;
  __syncthreads();
  float tot = red[0]+red[1]+red[2]+red[3];
  float inv = 1.f/fmaxf(sqrtf(tot), 1e-12f);
  float* dst = xf + (size_t)row*OC3;
  #pragma unroll
  for (int j = 0; j < 4; ++j) dst[t + j*256] = v[j]*inv;
}

__global__ __launch_bounds__(256) void final_mlp(const float* __restrict__ vlad, const float* __restrict__ xf,
    const float* __restrict__ W, const float* __restrict__ b, float* __restrict__ out){
  __shared__ float feat[9216];
  __shared__ float red[4];
  int row = blockIdx.x, t = threadIdx.x;
  {
    const float4* v = (const float4*)(vlad + (size_t)row*8192);
    float4* f4 = (float4*)feat;
    for (int i = t; i < 2048; i += 256) f4[i] = v[i];
    const float4* xv = (const float4*)(xf + (size_t)row*1024);
    if (t < 256) f4[2048 + t] = xv[t];
  }
  __syncthreads();
  const float* wr = W + (size_t)t*9216;
  float acc = b[t];
  for (int i = 0; i < 9216; i += 4){
    float4 wv = *(const float4*)&wr[i];
    acc += feat[i]*wv.x + feat[i+1]*wv.y + feat[i+2]*wv.z + feat[i+3]*wv.w;
  }
  float ss = acc*acc;
  #pragma unroll
  for (int m = 1; m < 64; m <<= 1) ss += __shfl_xor(ss, m);
  if ((t & 63) == 0) red[t >> 6] = ss;
  __syncthreads();
  float tot = red[0]+red[1]+red[2]+red[3];
  float inv = 1.f/fmaxf(sqrtf(tot), 1e-12f);
  out[(size_t)row*256 + t] = acc*inv;
}

// ---------------- launch ----------------
extern "C" void kernel_launch(void* const* d_in, const int* in_sizes, int n_in,
                              void* d_out, int out_size, void* d_ws, size_t ws_size,
                              hipStream_t stream){
  const float* x       = (const float*)d_in[0];
  const float* centers = (const float*)d_in[1];
  const float* conv_w  = (const float*)d_in[2];
  const float* conv_b  = (const float*)d_in[3];
  const float* w1      = (const float*)d_in[4];
  const float* b1      = (const float*)d_in[5];
  const float* w2      = (const float*)d_in[6];
  const float* b2      = (const float*)d_in[7];
  const float* w3      = (const float*)d_in[8];
  const float* b3      = (const float*)d_in[9];
  const float* mlp_w   = (const float*)d_in[10];
  const float* mlp_b   = (const float*)d_in[11];
  float* out = (float*)d_out;
  char* ws = (char*)d_ws;
  const size_t MB = 1ull << 20;
  if (ws_size < 248*MB) return;

  // persistent small buffers
  float* vlad  = (float*)(ws + 0);        // 3.75 MiB
  float* xf    = (float*)(ws + 4*MB);     // 0.47 MiB
  float* xfraw = (float*)(ws + 5*MB);     // 1.97 MiB
  char*  AR    = ws + 7*MB;               // arena (241 MiB), phase-reused
  // VLAD phase
  float* xt = (float*)(AR + 0);           // 84.4 MiB
  float* a  = (float*)(AR + 85*MB);       // 42.2 MiB (dead after vlad_xa2)
  float* ps = (float*)(AR + 128*MB);      // 14.4 MiB (dead after vlad_win2)
  // conv phase (after vlad_win2; regions recycled, stream-ordered)
  u16* xpb = (u16*)(AR + 0);              // 54.4 MiB (over xt)
  u16* wp1 = (u16*)(AR + 55*MB);          // 1.6 MiB
  u16* wp2 = (u16*)(AR + 57*MB);          // 6.25 MiB
  u16* wp3 = (u16*)(AR + 64*MB);          // 25 MiB
  u16* h1  = (u16*)(AR + 89*MB);          // 108.75 MiB (over a/ps)
  u16* p1  = (u16*)(AR + 0);              // 36.25 MiB (over xpb, dead after conv1)
  u16* h2  = (u16*)(AR + 89*MB);          // 72.5 MiB (over h1, dead after pool1)
  u16* p2  = (u16*)(AR + 163*MB);         // 18.1 MiB (past h2)
  u16* h3  = (u16*)(AR + 0);              // 36.25 MiB (over p1, dead after conv2)

  // ---- VLAD (fp32) ----
  transpose_xt<<<dim3(29,192,NB), 256, 0, stream>>>(x, xt);
  vlad_softmax<<<dim3(4,HH,NB), 256, 0, stream>>>(x, conv_w, conv_b, a);
  vlad_xa2<<<dim3(110,NB), 256, 0, stream>>>(xt, a, centers, ps);
  vlad_win2<<<dim3(KC,NT,NB), 128, 0, stream>>>(ps, vlad);
  vlad_gnorm<<<dim3(NB*NT), 256, 0, stream>>>(vlad);

  // ---- conv tower (bf16 MFMA) ----
  pack_w<<<dim3(3200),  256, 0, stream>>>(w1, wp1, OC1, DIM);
  pack_w<<<dim3(12800), 256, 0, stream>>>(w2, wp2, OC2, OC1);
  pack_w<<<dim3(51200), 256, 0, stream>>>(w3, wp3, OC3, OC2);
  build_xpb<<<dim3(37,HH,NB), 256, 0, stream>>>(x, xpb);
  conv5x5<128,256,48><<<dim3(9, OC1/128, NB*24), 512, 0, stream>>>(xpb, wp1, b1, h1);
  pool1k<<<dim3(WST/4,16,NB), 256, 0, stream>>>(h1, p1);
  conv5x5<256,512,16><<<dim3(9, OC2/128, NB*8), 512, 0, stream>>>(p1, wp2, b2, h2);
  pool2k<<<dim3(WST/2,4,NB), 256, 0, stream>>>(h2, p2);
  conv5x5<512,1024,4><<<dim3(9, OC3/128, NB*2), 512, 0, stream>>>(p2, wp3, b3, h3);
  pool3k<<<dim3(NT,4,NB), 256, 0, stream>>>(h3, xfraw);
  xf_norm<<<dim3(NB*NT), 256, 0, stream>>>(xfraw, xf);

  // ---- head ----
  final_mlp<<<dim3(NB*NT), 256, 0, stream>>>(vlad, xf, mlp_w, mlp_b, out);
}

// Round 7
// 2277.361 us; speedup vs baseline: 1.9029x; 1.0490x over previous
//
#include <hip/hip_runtime.h>
#include <hip/hip_bf16.h>

// ---------------- constants ----------------
#define NB   4
#define DIM  128
#define KC   64
#define HH   48
#define WW   900
#define WPAD 1100
#define WST  1160   // guarded stride for conv-phase buffers: col = w + 2, zeros outside [0,1100)
#define NT   30
#define OC1  256
#define OC2  512
#define OC3  1024

typedef __attribute__((ext_vector_type(8))) short bf16x8;
typedef __attribute__((ext_vector_type(4))) float f32x4;
typedef unsigned short u16;
typedef unsigned int u32;

__device__ __forceinline__ u16 f2bf(float f){
  __hip_bfloat16 h = __float2bfloat16(f);
  u16 u; __builtin_memcpy(&u, &h, 2); return u;
}
__device__ __forceinline__ float bf2f(u16 u){
  __hip_bfloat16 h; __builtin_memcpy(&h, &u, 2); return __bfloat162float(h);
}

typedef __attribute__((address_space(1))) const u32 g_u32;
typedef __attribute__((address_space(3))) u32 l_u32;
// async global->LDS, 16B per lane; LDS dest = uniform base + lane*16
__device__ __forceinline__ void gll16(const void* g, void* l){
  __builtin_amdgcn_global_load_lds((g_u32*)g, (l_u32*)l, 16, 0, 0);
}

// ---------------- VLAD branch (fp32) ----------------

__global__ __launch_bounds__(256) void transpose_xt(const float* __restrict__ x, float* __restrict__ xt){
  __shared__ float tile[32][33];
  int n = blockIdx.z;
  int r0 = blockIdx.y*32, w0 = blockIdx.x*32;
  int t = threadIdx.x;
  int tr = t >> 5, tc = t & 31;
  #pragma unroll
  for (int i = 0; i < 4; ++i){
    int r = r0 + tr + i*8, w = w0 + tc;
    tile[tr + i*8][tc] = (w < WW) ? x[((size_t)n*(DIM*HH) + r)*WW + w] : 0.f;
  }
  __syncthreads();
  #pragma unroll
  for (int i = 0; i < 4; ++i){
    int w = w0 + tr + i*8, r = r0 + tc;
    if (w < WW) xt[((size_t)n*WW + w)*(DIM*HH) + r] = tile[tc][tr + i*8];
  }
}

__global__ __launch_bounds__(256) void vlad_softmax(const float* __restrict__ x,
    const float* __restrict__ conv_w, const float* __restrict__ conv_b, float* __restrict__ a){
  __shared__ float cwT[DIM*KC];
  __shared__ float cbs[KC];
  int t = threadIdx.x;
  for (int i = t; i < DIM*KC; i += 256){ int c = i >> 6, k = i & 63; cwT[i] = conv_w[k*DIM + c]; }
  if (t < KC) cbs[t] = conv_b[t];
  __syncthreads();
  int w = blockIdx.x*256 + t, h = blockIdx.y, n = blockIdx.z;
  bool ok = (w < WW);
  float lg[KC];
  #pragma unroll
  for (int k = 0; k < KC; ++k) lg[k] = cbs[k];
  const float* xp = x + (size_t)n*DIM*HH*WW + (size_t)h*WW + (ok ? w : 0);
  for (int c = 0; c < DIM; ++c){
    float xv = ok ? xp[(size_t)c*HH*WW] : 0.f;
    const float* cw = &cwT[c*KC];
    #pragma unroll
    for (int k = 0; k < KC; ++k) lg[k] += xv * cw[k];
  }
  float m = lg[0];
  #pragma unroll
  for (int k = 1; k < KC; ++k) m = fmaxf(m, lg[k]);
  float s = 0.f;
  #pragma unroll
  for (int k = 0; k < KC; ++k){ lg[k] = __expf(lg[k]-m); s += lg[k]; }
  float inv = 1.f/s;
  if (ok){
    float* dst = a + (((size_t)(n*HH + h))*WW + w)*KC;
    #pragma unroll
    for (int k = 0; k < KC; k += 4){
      float4 v = make_float4(lg[k]*inv, lg[k+1]*inv, lg[k+2]*inv, lg[k+3]*inv);
      *(float4*)&dst[k] = v;
    }
  }
}

// fused: per (n, segment s of 10 padded-w positions) accumulate
// ps[k][c] = sum_{w in seg} ( sum_h a[k,h,w]*x[c,h,w] ) - centers[k][c] * sum_{w in seg} sum_h a[k,h,w]
__global__ __launch_bounds__(256) void vlad_xa2(const float* __restrict__ xt, const float* __restrict__ a,
    const float* __restrict__ centers, float* __restrict__ ps){
  __shared__ float aT[HH][KC];
  __shared__ float xT[DIM*HH];
  int t = threadIdx.x, s = blockIdx.x, n = blockIdx.y;
  int k = t >> 2, cb4 = t & 3;
  float acc[32];
  #pragma unroll
  for (int j = 0; j < 32; ++j) acc[j] = 0.f;
  float Sacc = 0.f;
  for (int i = 0; i < 10; ++i){
    int p = s*10 + i;
    int w = (p < 100) ? p + 800 : ((p < 1000) ? p - 100 : p - 1000);
    for (int e = t; e < HH*KC; e += 256){
      int h = e >> 6, kk = e & 63;
      aT[h][kk] = a[(((size_t)(n*HH + h))*WW + w)*KC + kk];
    }
    {
      const float4* src = (const float4*)(xt + ((size_t)n*WW + w)*(DIM*HH));
      float4* dst4 = (float4*)xT;
      for (int e = t; e < (DIM*HH)/4; e += 256) dst4[e] = src[e];
    }
    __syncthreads();
    float areg[HH];
    #pragma unroll
    for (int h = 0; h < HH; ++h) areg[h] = aT[h][k];
    float Sw = 0.f;
    #pragma unroll
    for (int h = 0; h < HH; ++h) Sw += areg[h];
    Sacc += Sw;
    #pragma unroll 2
    for (int j = 0; j < 32; ++j){
      const float4* xr = (const float4*)&xT[(cb4 + 4*j)*HH];
      float sum = 0.f;
      #pragma unroll
      for (int h4 = 0; h4 < HH/4; ++h4){
        float4 xv = xr[h4];
        sum += areg[h4*4+0]*xv.x + areg[h4*4+1]*xv.y + areg[h4*4+2]*xv.z + areg[h4*4+3]*xv.w;
      }
      acc[j] += sum;
    }
    __syncthreads();
  }
  const float* ck = centers + (size_t)k*DIM;
  float* dst = ps + (((size_t)(n*KC + k))*110 + s)*DIM;
  #pragma unroll
  for (int j = 0; j < 32; ++j){
    int c = cb4 + 4*j;
    dst[c] = acc[j] - ck[c]*Sacc;
  }
}

// window tt = segments [3tt, 3tt+20); sum + intra (per-cluster) L2 norm
__global__ __launch_bounds__(128) void vlad_win2(const float* __restrict__ ps, float* __restrict__ vlad){
  int c = threadIdx.x, k = blockIdx.x, tt = blockIdx.y, n = blockIdx.z;
  const float* base = ps + ((size_t)(n*KC + k))*110*DIM + c;
  float v = 0.f;
  #pragma unroll
  for (int u = 0; u < 20; ++u) v += base[(3*tt + u)*DIM];
  float ss = v*v;
  #pragma unroll
  for (int m = 1; m < 64; m <<= 1) ss += __shfl_xor(ss, m);
  __shared__ float red[2];
  if ((c & 63) == 0) red[c >> 6] = ss;
  __syncthreads();
  float tot = red[0] + red[1];
  float inv = 1.f / fmaxf(sqrtf(tot), 1e-12f);
  vlad[(((size_t)(n*NT + tt))*KC + k)*DIM + c] = v*inv;
}

__global__ __launch_bounds__(256) void vlad_gnorm(float* __restrict__ vlad){
  int row = blockIdx.x, t = threadIdx.x;
  float4* v = (float4*)(vlad + (size_t)row*(KC*DIM));
  float4 r[8]; float ss = 0.f;
  #pragma unroll
  for (int i = 0; i < 8; ++i){
    r[i] = v[t + i*256];
    ss += r[i].x*r[i].x + r[i].y*r[i].y + r[i].z*r[i].z + r[i].w*r[i].w;
  }
  #pragma unroll
  for (int m = 1; m < 64; m <<= 1) ss += __shfl_xor(ss, m);
  __shared__ float red[4];
  if ((t & 63) == 0) red[t >> 6] = ss;
  __syncthreads();
  float tot = red[0]+red[1]+red[2]+red[3];
  float inv = 1.f / fmaxf(sqrtf(tot), 1e-12f);
  #pragma unroll
  for (int i = 0; i < 8; ++i){
    float4 o = r[i]; o.x*=inv; o.y*=inv; o.z*=inv; o.w*=inv;
    v[t + i*256] = o;
  }
}

// ---------------- conv tower (bf16 MFMA, NHWC, guarded stride WST) ----------------

__global__ __launch_bounds__(256) void build_xpb(const float* __restrict__ x, u16* __restrict__ xpb){
  __shared__ u16 tile[DIM][33];
  int t = threadIdx.x, h = blockIdx.y, n = blockIdx.z;
  int b0 = blockIdx.x*32;
  #pragma unroll
  for (int i = 0; i < 16; ++i){
    int e = t + i*256;
    int c = e >> 5, bl = e & 31;
    int b = b0 + bl, w = b - 2;
    float v = 0.f;
    if (w >= 0 && w < WPAD){
      int wsrc = (w + 800) % 900;
      v = x[((size_t)(n*DIM + c)*HH + h)*WW + wsrc];
    }
    tile[c][bl] = f2bf(v);
  }
  __syncthreads();
  #pragma unroll
  for (int i = 0; i < 16; ++i){
    int e = t + i*256;
    int bl = e >> 7, c = e & 127;
    int b = b0 + bl;
    if (b < WST) xpb[((size_t)(n*HH + h)*WST + b)*DIM + c] = tile[c][bl];
  }
}

__global__ __launch_bounds__(256) void pack_w(const float* __restrict__ w, u16* __restrict__ wp, int OC, int IC){
  int idx = blockIdx.x*256 + threadIdx.x;
  int total = OC*IC*25;
  if (idx >= total) return;
  int ic = idx % IC; int r = idx / IC; int oc = r % OC; int tap = r / OC;
  wp[idx] = f2bf(w[((size_t)oc*IC + ic)*25 + tap]);
}

// 5x5 conv pad 2, NHWC bf16, guarded input (round-2 structure: 128oc x 128w block,
// 4 waves of 64x64, single-buffered LDS, 66.5 KB -> 2 blocks/CU whose staggered
// phases provide the overlap; this empirically beats explicit pipelining here).
// + T5 setprio around the MFMA cluster (independent-blocks regime).
template<int IC, int OC, int H>
__global__ __launch_bounds__(256,2) void conv5x5(const u16* __restrict__ in, const u16* __restrict__ wp,
    const float* __restrict__ bias, u16* __restrict__ out){
  constexpr int NICB = IC/128;
  __shared__ u16 sIn[132*128];   // rows 0..131 = input w0-2 .. w0+129, 256B/row, chunk-swizzled
  __shared__ u16 sW[128*128];    // rows = oc local, chunk-swizzled
  int t = threadIdx.x;
  int wave = t >> 6, lane = t & 63, lr = lane & 15, lgp = lane >> 4;
  int w0  = blockIdx.x * 128;
  int ocb = blockIdx.y * 128;
  int nh = blockIdx.z; int n = nh / H, h = nh % H;
  int wo_oc = (wave & 1)*64, wo_w = (wave >> 1)*64;
  f32x4 acc[4][4] = {};
  const u16* inN = in + (size_t)n*H*WST*IC;   // col0 = w=-2
  for (int dh = 0; dh < 5; ++dh){
    int hin = h + dh - 2;
    if (hin < 0 || hin >= H) continue;
    const u16* rowbase = inN + (size_t)hin*WST*IC;
    for (int icb = 0; icb < NICB; ++icb){
      __syncthreads();  // prior reads of sIn/sW done before overwrite
      // stage sIn: 132 rows x 16 chunks = 2112 chunks = 33 gll instrs
      for (int i = wave; i < 33; i += 4){
        int qq = i*64 + lane;
        int r = qq >> 4, cp = qq & 15;
        int c = cp ^ (r & 7);
        gll16(rowbase + (size_t)(w0 + r)*IC + icb*128 + c*8, &sIn[i*512]);
      }
      for (int dw = 0; dw < 5; ++dw){
        if (dw) __syncthreads();  // waves done reading previous sW
        {
          int tap = dh*5 + dw;
          const u16* wsrc = wp + ((size_t)tap*OC + ocb)*IC + (size_t)icb*128;
          for (int i = wave; i < 32; i += 4){
            int qq = i*64 + lane;
            int r = qq >> 4, cp = qq & 15;
            int c = cp ^ (r & 7);
            gll16(wsrc + (size_t)r*IC + c*8, &sW[i*512]);
          }
        }
        __syncthreads();  // staging complete (vmcnt drained by barrier)
        __builtin_amdgcn_s_setprio(1);
        #pragma unroll
        for (int k0i = 0; k0i < 4; ++k0i){
          bf16x8 A[4], B[4];
          #pragma unroll
          for (int j = 0; j < 4; ++j){
            int ar = wo_oc + j*16 + lr;
            A[j] = *(const bf16x8*)&sW[ar*128 + (((k0i*4 + lgp) ^ (lr & 7)) << 3)];
            int br = wo_w + j*16 + lr + dw;
            B[j] = *(const bf16x8*)&sIn[br*128 + (((k0i*4 + lgp) ^ (br & 7)) << 3)];
          }
          #pragma unroll
          for (int ja = 0; ja < 4; ++ja)
            #pragma unroll
            for (int jb = 0; jb < 4; ++jb)
              acc[ja][jb] = __builtin_amdgcn_mfma_f32_16x16x32_bf16(A[ja], B[jb], acc[ja][jb], 0, 0, 0);
        }
        __builtin_amdgcn_s_setprio(0);
      }
    }
  }
  u16* outP = out + ((size_t)(n*H + h)*WST + 2)*OC;  // col = w+2
  #pragma unroll
  for (int ja = 0; ja < 4; ++ja){
    int oc = ocb + wo_oc + ja*16 + lgp*4;
    float4 bv = *(const float4*)&bias[oc];
    #pragma unroll
    for (int jb = 0; jb < 4; ++jb){
      int wg = w0 + wo_w + jb*16 + lr;
      if (wg < WPAD){
        f32x4 av = acc[ja][jb];
        ushort4 o;
        o.x = f2bf(av[0] + bv.x);
        o.y = f2bf(av[1] + bv.y);
        o.z = f2bf(av[2] + bv.z);
        o.w = f2bf(av[3] + bv.w);
        *(ushort4*)(outP + (size_t)wg*OC + oc) = o;
      }
    }
  }
}

// leaky(0.2) + maxpool 3x3 stride(3,1); 4 oc/thread (8B loads); writes full guarded range
__global__ __launch_bounds__(256) void pool1k(const u16* __restrict__ in, u16* __restrict__ out){
  int t = threadIdx.x;
  int wb = blockIdx.x*4 + (t >> 6);
  int oc = (t & 63)*4;
  int ho = blockIdx.y, n = blockIdx.z;
  int wo = wb - 2;
  float m0=0.f,m1=0.f,m2=0.f,m3=0.f;
  if (wo >= 0 && wo < WPAD){
    m0=m1=m2=m3=-1e30f;
    #pragma unroll
    for (int kh = 0; kh < 3; ++kh){
      const u16* row = in + ((size_t)(n*HH + ho*3 + kh)*WST + 2)*OC1 + oc;
      #pragma unroll
      for (int kw = 0; kw < 3; ++kw){
        int wi = wo - 1 + kw;
        if (wi >= 0 && wi < WPAD){
          ushort4 v = *(const ushort4*)(row + (size_t)wi*OC1);
          m0 = fmaxf(m0, bf2f(v.x)); m1 = fmaxf(m1, bf2f(v.y));
          m2 = fmaxf(m2, bf2f(v.z)); m3 = fmaxf(m3, bf2f(v.w));
        }
      }
    }
    m0 = (m0>0.f)?m0:0.2f*m0; m1 = (m1>0.f)?m1:0.2f*m1;
    m2 = (m2>0.f)?m2:0.2f*m2; m3 = (m3>0.f)?m3:0.2f*m3;
  }
  ushort4 o; o.x=f2bf(m0); o.y=f2bf(m1); o.z=f2bf(m2); o.w=f2bf(m3);
  *(ushort4*)(out + ((size_t)(n*16 + ho)*WST + wb)*OC1 + oc) = o;
}

// leaky(0.2) + maxpool 4x5 stride(4,1); 4 oc/thread
__global__ __launch_bounds__(256) void pool2k(const u16* __restrict__ in, u16* __restrict__ out){
  int t = threadIdx.x;
  int wb = blockIdx.x*2 + (t >> 7);
  int oc = (t & 127)*4;
  int ho = blockIdx.y, n = blockIdx.z;
  int wo = wb - 2;
  float m0=0.f,m1=0.f,m2=0.f,m3=0.f;
  if (wo >= 0 && wo < WPAD){
    m0=m1=m2=m3=-1e30f;
    #pragma unroll
    for (int kh = 0; kh < 4; ++kh){
      const u16* row = in + ((size_t)(n*16 + ho*4 + kh)*WST + 2)*OC2 + oc;
      #pragma unroll
      for (int kw = 0; kw < 5; ++kw){
        int wi = wo - 2 + kw;
        if (wi >= 0 && wi < WPAD){
          ushort4 v = *(const ushort4*)(row + (size_t)wi*OC2);
          m0 = fmaxf(m0, bf2f(v.x)); m1 = fmaxf(m1, bf2f(v.y));
          m2 = fmaxf(m2, bf2f(v.z)); m3 = fmaxf(m3, bf2f(v.w));
        }
      }
    }
    m0 = (m0>0.f)?m0:0.2f*m0; m1 = (m1>0.f)?m1:0.2f*m1;
    m2 = (m2>0.f)?m2:0.2f*m2; m3 = (m3>0.f)?m3:0.2f*m3;
  }
  ushort4 o; o.x=f2bf(m0); o.y=f2bf(m1); o.z=f2bf(m2); o.w=f2bf(m3);
  *(ushort4*)(out + ((size_t)(n*4 + ho)*WST + wb)*OC2 + oc) = o;
}

// maxpool 1x200 over one h-row, sampled every 30; partials per h -> xfraw [n][t][4][1024]
__global__ __launch_bounds__(256) void pool3k(const u16* __restrict__ in, float* __restrict__ xfraw){
  int tt = blockIdx.x, hh = blockIdx.y, n = blockIdx.z;
  int oc = threadIdx.x*4;
  float m0=-1e30f,m1=-1e30f,m2=-1e30f,m3=-1e30f;
  const u16* row = in + ((size_t)(n*4 + hh)*WST + 2 + 30*tt)*OC3 + oc;
  for (int p = 0; p < 200; ++p){
    ushort4 v = *(const ushort4*)(row + (size_t)p*OC3);
    m0 = fmaxf(m0, bf2f(v.x)); m1 = fmaxf(m1, bf2f(v.y));
    m2 = fmaxf(m2, bf2f(v.z)); m3 = fmaxf(m3, bf2f(v.w));
  }
  float* dst = xfraw + (((size_t)(n*NT + tt))*4 + hh)*OC3 + oc;
  dst[0]=m0; dst[1]=m1; dst[2]=m2; dst[3]=m3;
}

// combine 4 h-partials, L2 normalize -> xf [row][1024]
__global__ __launch_bounds__(256) void xf_norm(const float* __restrict__ xfraw, float* __restrict__ xf){
  int row = blockIdx.x, t = threadIdx.x;
  const float* src = xfraw + (size_t)row*4096;
  float v[4]; float ss = 0.f;
  #pragma unroll
  for (int j = 0; j < 4; ++j){
    float m = src[t + j*256];
    #pragma unroll
    for (int hh = 1; hh < 4; ++hh) m = fmaxf(m, src[hh*1024 + t + j*256]);
    v[j] = m; ss += m*m;
  }
  #pragma unroll
  for (int m = 1; m < 64; m <<= 1) ss += __shfl_xor(ss, m);
  __shared__ float red[4];
  if ((t & 63) == 0) red[t >> 6] = ss;
  __syncthreads();
  float tot = red[0]+red[1]+red[2]+red[3];
  float inv = 1.f/fmaxf(sqrtf(tot), 1e-12f);
  float* dst = xf + (size_t)row*OC3;
  #pragma unroll
  for (int j = 0; j < 4; ++j) dst[t + j*256] = v[j]*inv;
}

// 4 output rows per block (grid 30): W slice streamed once per 4 rows instead of
// once per row (120x9.4MB -> 30x9.4MB); feat chunked through LDS. Exact fp32.
__global__ __launch_bounds__(256) void final_mlp4(const float* __restrict__ vlad, const float* __restrict__ xf,
    const float* __restrict__ W, const float* __restrict__ b, float* __restrict__ out){
  __shared__ float feat[4][1152];
  __shared__ float red2[4][4];
  int rb = blockIdx.x, t = threadIdx.x;
  float bt = b[t];
  float acc[4];
  #pragma unroll
  for (int r = 0; r < 4; ++r) acc[r] = bt;
  for (int ch = 0; ch < 8; ++ch){
    __syncthreads();
    for (int e = t; e < 1152; e += 256){
      int r = e / 288, i4 = (e % 288)*4;
      int i = ch*1152 + i4;
      int row = rb*4 + r;
      float4 v = (i < 8192) ? *(const float4*)&vlad[(size_t)row*8192 + i]
                            : *(const float4*)&xf[(size_t)row*1024 + (i - 8192)];
      *(float4*)&feat[r][i4] = v;
    }
    __syncthreads();
    const float* wr = W + (size_t)t*9216 + ch*1152;
    for (int i = 0; i < 1152; i += 4){
      float4 wv = *(const float4*)&wr[i];
      #pragma unroll
      for (int r = 0; r < 4; ++r)
        acc[r] += feat[r][i]*wv.x + feat[r][i+1]*wv.y + feat[r][i+2]*wv.z + feat[r][i+3]*wv.w;
    }
  }
  float ss[4];
  #pragma unroll
  for (int r = 0; r < 4; ++r){
    ss[r] = acc[r]*acc[r];
    #pragma unroll
    for (int m = 1; m < 64; m <<= 1) ss[r] += __shfl_xor(ss[r], m);
  }
  if ((t & 63) == 0){
    int wv = t >> 6;
    #pragma unroll
    for (int r = 0; r < 4; ++r) red2[wv][r] = ss[r];
  }
  __syncthreads();
  #pragma unroll
  for (int r = 0; r < 4; ++r){
    float tot = red2[0][r] + red2[1][r] + red2[2][r] + red2[3][r];
    float inv = 1.f/fmaxf(sqrtf(tot), 1e-12f);
    out[(size_t)(rb*4 + r)*256 + t] = acc[r]*inv;
  }
}

// ---------------- launch ----------------
extern "C" void kernel_launch(void* const* d_in, const int* in_sizes, int n_in,
                              void* d_out, int out_size, void* d_ws, size_t ws_size,
                              hipStream_t stream){
  const float* x       = (const float*)d_in[0];
  const float* centers = (const float*)d_in[1];
  const float* conv_w  = (const float*)d_in[2];
  const float* conv_b  = (const float*)d_in[3];
  const float* w1      = (const float*)d_in[4];
  const float* b1      = (const float*)d_in[5];
  const float* w2      = (const float*)d_in[6];
  const float* b2      = (const float*)d_in[7];
  const float* w3      = (const float*)d_in[8];
  const float* b3      = (const float*)d_in[9];
  const float* mlp_w   = (const float*)d_in[10];
  const float* mlp_b   = (const float*)d_in[11];
  float* out = (float*)d_out;
  char* ws = (char*)d_ws;
  const size_t MB = 1ull << 20;
  if (ws_size < 248*MB) return;

  // persistent small buffers
  float* vlad  = (float*)(ws + 0);        // 3.75 MiB
  float* xf    = (float*)(ws + 4*MB);     // 0.47 MiB
  float* xfraw = (float*)(ws + 5*MB);     // 1.97 MiB
  char*  AR    = ws + 7*MB;               // arena (241 MiB), phase-reused
  // VLAD phase
  float* xt = (float*)(AR + 0);           // 84.4 MiB
  float* a  = (float*)(AR + 85*MB);       // 42.2 MiB (dead after vlad_xa2)
  float* ps = (float*)(AR + 128*MB);      // 14.4 MiB (dead after vlad_win2)
  // conv phase (after vlad_win2; regions recycled, stream-ordered)
  u16* xpb = (u16*)(AR + 0);              // 54.4 MiB (over xt)
  u16* wp1 = (u16*)(AR + 55*MB);          // 1.6 MiB
  u16* wp2 = (u16*)(AR + 57*MB);          // 6.25 MiB
  u16* wp3 = (u16*)(AR + 64*MB);          // 25 MiB
  u16* h1  = (u16*)(AR + 89*MB);          // 108.75 MiB (over a/ps)
  u16* p1  = (u16*)(AR + 0);              // 36.25 MiB (over xpb, dead after conv1)
  u16* h2  = (u16*)(AR + 89*MB);          // 72.5 MiB (over h1, dead after pool1)
  u16* p2  = (u16*)(AR + 163*MB);         // 18.1 MiB (past h2)
  u16* h3  = (u16*)(AR + 0);              // 36.25 MiB (over p1, dead after conv2)

  // ---- VLAD (fp32) ----
  transpose_xt<<<dim3(29,192,NB), 256, 0, stream>>>(x, xt);
  vlad_softmax<<<dim3(4,HH,NB), 256, 0, stream>>>(x, conv_w, conv_b, a);
  vlad_xa2<<<dim3(110,NB), 256, 0, stream>>>(xt, a, centers, ps);
  vlad_win2<<<dim3(KC,NT,NB), 128, 0, stream>>>(ps, vlad);
  vlad_gnorm<<<dim3(NB*NT), 256, 0, stream>>>(vlad);

  // ---- conv tower (bf16 MFMA) ----
  pack_w<<<dim3(3200),  256, 0, stream>>>(w1, wp1, OC1, DIM);
  pack_w<<<dim3(12800), 256, 0, stream>>>(w2, wp2, OC2, OC1);
  pack_w<<<dim3(51200), 256, 0, stream>>>(w3, wp3, OC3, OC2);
  build_xpb<<<dim3(37,HH,NB), 256, 0, stream>>>(x, xpb);
  conv5x5<128,256,48><<<dim3(9, OC1/128, NB*HH), 256, 0, stream>>>(xpb, wp1, b1, h1);
  pool1k<<<dim3(WST/4,16,NB), 256, 0, stream>>>(h1, p1);
  conv5x5<256,512,16><<<dim3(9, OC2/128, NB*16), 256, 0, stream>>>(p1, wp2, b2, h2);
  pool2k<<<dim3(WST/2,4,NB), 256, 0, stream>>>(h2, p2);
  conv5x5<512,1024,4><<<dim3(9, OC3/128, NB*4), 256, 0, stream>>>(p2, wp3, b3, h3);
  pool3k<<<dim3(NT,4,NB), 256, 0, stream>>>(h3, xfraw);
  xf_norm<<<dim3(NB*NT), 256, 0, stream>>>(xfraw, xf);

  // ---- head ----
  final_mlp4<<<dim3(NB*NT/4), 256, 0, stream>>>(vlad, xf, mlp_w, mlp_b, out);
}

// Round 8
// 1848.308 us; speedup vs baseline: 2.3446x; 1.2321x over previous
//
#include <hip/hip_runtime.h>
#include <hip/hip_bf16.h>

// ---------------- constants ----------------
#define NB   4
#define DIM  128
#define KC   64
#define HH   48
#define WW   900
#define WPAD 1100
#define WST  1160   // guarded stride for conv-phase buffers: col = w + 2, zeros outside [0,1100)
#define NT   30
#define OC1  256
#define OC2  512
#define OC3  1024

typedef __attribute__((ext_vector_type(8))) short bf16x8;
typedef __attribute__((ext_vector_type(4))) float f32x4;
typedef unsigned short u16;
typedef unsigned int u32;

__device__ __forceinline__ u16 f2bf(float f){
  __hip_bfloat16 h = __float2bfloat16(f);
  u16 u; __builtin_memcpy(&u, &h, 2); return u;
}
__device__ __forceinline__ float bf2f(u16 u){
  __hip_bfloat16 h; __builtin_memcpy(&h, &u, 2); return __bfloat162float(h);
}

typedef __attribute__((address_space(1))) const u32 g_u32;
typedef __attribute__((address_space(3))) u32 l_u32;
// async global->LDS, 16B per lane; LDS dest = uniform base + lane*16
__device__ __forceinline__ void gll16(const void* g, void* l){
  __builtin_amdgcn_global_load_lds((g_u32*)g, (l_u32*)l, 16, 0, 0);
}

// ---------------- VLAD branch (fp32) ----------------

__global__ __launch_bounds__(256) void transpose_xt(const float* __restrict__ x, float* __restrict__ xt){
  __shared__ float tile[32][33];
  int n = blockIdx.z;
  int r0 = blockIdx.y*32, w0 = blockIdx.x*32;
  int t = threadIdx.x;
  int tr = t >> 5, tc = t & 31;
  #pragma unroll
  for (int i = 0; i < 4; ++i){
    int r = r0 + tr + i*8, w = w0 + tc;
    tile[tr + i*8][tc] = (w < WW) ? x[((size_t)n*(DIM*HH) + r)*WW + w] : 0.f;
  }
  __syncthreads();
  #pragma unroll
  for (int i = 0; i < 4; ++i){
    int w = w0 + tr + i*8, r = r0 + tc;
    if (w < WW) xt[((size_t)n*WW + w)*(DIM*HH) + r] = tile[tc][tr + i*8];
  }
}

__global__ __launch_bounds__(256) void vlad_softmax(const float* __restrict__ x,
    const float* __restrict__ conv_w, const float* __restrict__ conv_b, float* __restrict__ a){
  __shared__ float cwT[DIM*KC];
  __shared__ float cbs[KC];
  int t = threadIdx.x;
  for (int i = t; i < DIM*KC; i += 256){ int c = i >> 6, k = i & 63; cwT[i] = conv_w[k*DIM + c]; }
  if (t < KC) cbs[t] = conv_b[t];
  __syncthreads();
  int w = blockIdx.x*256 + t, h = blockIdx.y, n = blockIdx.z;
  bool ok = (w < WW);
  float lg[KC];
  #pragma unroll
  for (int k = 0; k < KC; ++k) lg[k] = cbs[k];
  const float* xp = x + (size_t)n*DIM*HH*WW + (size_t)h*WW + (ok ? w : 0);
  for (int c = 0; c < DIM; ++c){
    float xv = ok ? xp[(size_t)c*HH*WW] : 0.f;
    const float* cw = &cwT[c*KC];
    #pragma unroll
    for (int k = 0; k < KC; ++k) lg[k] += xv * cw[k];
  }
  float m = lg[0];
  #pragma unroll
  for (int k = 1; k < KC; ++k) m = fmaxf(m, lg[k]);
  float s = 0.f;
  #pragma unroll
  for (int k = 0; k < KC; ++k){ lg[k] = __expf(lg[k]-m); s += lg[k]; }
  float inv = 1.f/s;
  if (ok){
    float* dst = a + (((size_t)(n*HH + h))*WW + w)*KC;
    #pragma unroll
    for (int k = 0; k < KC; k += 4){
      float4 v = make_float4(lg[k]*inv, lg[k+1]*inv, lg[k+2]*inv, lg[k+3]*inv);
      *(float4*)&dst[k] = v;
    }
  }
}

// fused: per (n, segment s of 10 padded-w positions) accumulate
// ps[k][c] = sum_{w in seg} ( sum_h a[k,h,w]*x[c,h,w] ) - centers[k][c] * sum_{w in seg} sum_h a[k,h,w]
__global__ __launch_bounds__(256) void vlad_xa2(const float* __restrict__ xt, const float* __restrict__ a,
    const float* __restrict__ centers, float* __restrict__ ps){
  __shared__ float aT[HH][KC];
  __shared__ float xT[DIM*HH];
  int t = threadIdx.x, s = blockIdx.x, n = blockIdx.y;
  int k = t >> 2, cb4 = t & 3;
  float acc[32];
  #pragma unroll
  for (int j = 0; j < 32; ++j) acc[j] = 0.f;
  float Sacc = 0.f;
  for (int i = 0; i < 10; ++i){
    int p = s*10 + i;
    int w = (p < 100) ? p + 800 : ((p < 1000) ? p - 100 : p - 1000);
    for (int e = t; e < HH*KC; e += 256){
      int h = e >> 6, kk = e & 63;
      aT[h][kk] = a[(((size_t)(n*HH + h))*WW + w)*KC + kk];
    }
    {
      const float4* src = (const float4*)(xt + ((size_t)n*WW + w)*(DIM*HH));
      float4* dst4 = (float4*)xT;
      for (int e = t; e < (DIM*HH)/4; e += 256) dst4[e] = src[e];
    }
    __syncthreads();
    float areg[HH];
    #pragma unroll
    for (int h = 0; h < HH; ++h) areg[h] = aT[h][k];
    float Sw = 0.f;
    #pragma unroll
    for (int h = 0; h < HH; ++h) Sw += areg[h];
    Sacc += Sw;
    #pragma unroll 2
    for (int j = 0; j < 32; ++j){
      const float4* xr = (const float4*)&xT[(cb4 + 4*j)*HH];
      float sum = 0.f;
      #pragma unroll
      for (int h4 = 0; h4 < HH/4; ++h4){
        float4 xv = xr[h4];
        sum += areg[h4*4+0]*xv.x + areg[h4*4+1]*xv.y + areg[h4*4+2]*xv.z + areg[h4*4+3]*xv.w;
      }
      acc[j] += sum;
    }
    __syncthreads();
  }
  const float* ck = centers + (size_t)k*DIM;
  float* dst = ps + (((size_t)(n*KC + k))*110 + s)*DIM;
  #pragma unroll
  for (int j = 0; j < 32; ++j){
    int c = cb4 + 4*j;
    dst[c] = acc[j] - ck[c]*Sacc;
  }
}

// window tt = segments [3tt, 3tt+20); sum + intra (per-cluster) L2 norm
__global__ __launch_bounds__(128) void vlad_win2(const float* __restrict__ ps, float* __restrict__ vlad){
  int c = threadIdx.x, k = blockIdx.x, tt = blockIdx.y, n = blockIdx.z;
  const float* base = ps + ((size_t)(n*KC + k))*110*DIM + c;
  float v = 0.f;
  #pragma unroll
  for (int u = 0; u < 20; ++u) v += base[(3*tt + u)*DIM];
  float ss = v*v;
  #pragma unroll
  for (int m = 1; m < 64; m <<= 1) ss += __shfl_xor(ss, m);
  __shared__ float red[2];
  if ((c & 63) == 0) red[c >> 6] = ss;
  __syncthreads();
  float tot = red[0] + red[1];
  float inv = 1.f / fmaxf(sqrtf(tot), 1e-12f);
  vlad[(((size_t)(n*NT + tt))*KC + k)*DIM + c] = v*inv;
}

__global__ __launch_bounds__(256) void vlad_gnorm(float* __restrict__ vlad){
  int row = blockIdx.x, t = threadIdx.x;
  float4* v = (float4*)(vlad + (size_t)row*(KC*DIM));
  float4 r[8]; float ss = 0.f;
  #pragma unroll
  for (int i = 0; i < 8; ++i){
    r[i] = v[t + i*256];
    ss += r[i].x*r[i].x + r[i].y*r[i].y + r[i].z*r[i].z + r[i].w*r[i].w;
  }
  #pragma unroll
  for (int m = 1; m < 64; m <<= 1) ss += __shfl_xor(ss, m);
  __shared__ float red[4];
  if ((t & 63) == 0) red[t >> 6] = ss;
  __syncthreads();
  float tot = red[0]+red[1]+red[2]+red[3];
  float inv = 1.f / fmaxf(sqrtf(tot), 1e-12f);
  #pragma unroll
  for (int i = 0; i < 8; ++i){
    float4 o = r[i]; o.x*=inv; o.y*=inv; o.z*=inv; o.w*=inv;
    v[t + i*256] = o;
  }
}

// ---------------- conv tower (bf16 MFMA, NHWC, guarded stride WST) ----------------

__global__ __launch_bounds__(256) void build_xpb(const float* __restrict__ x, u16* __restrict__ xpb){
  __shared__ u16 tile[DIM][33];
  int t = threadIdx.x, h = blockIdx.y, n = blockIdx.z;
  int b0 = blockIdx.x*32;
  #pragma unroll
  for (int i = 0; i < 16; ++i){
    int e = t + i*256;
    int c = e >> 5, bl = e & 31;
    int b = b0 + bl, w = b - 2;
    float v = 0.f;
    if (w >= 0 && w < WPAD){
      int wsrc = (w + 800) % 900;
      v = x[((size_t)(n*DIM + c)*HH + h)*WW + wsrc];
    }
    tile[c][bl] = f2bf(v);
  }
  __syncthreads();
  #pragma unroll
  for (int i = 0; i < 16; ++i){
    int e = t + i*256;
    int bl = e >> 7, c = e & 127;
    int b = b0 + bl;
    if (b < WST) xpb[((size_t)(n*HH + h)*WST + b)*DIM + c] = tile[c][bl];
  }
}

__global__ __launch_bounds__(256) void pack_w(const float* __restrict__ w, u16* __restrict__ wp, int OC, int IC){
  int idx = blockIdx.x*256 + threadIdx.x;
  int total = OC*IC*25;
  if (idx >= total) return;
  int ic = idx % IC; int r = idx / IC; int oc = r % OC; int tap = r / OC;
  wp[idx] = f2bf(w[((size_t)oc*IC + ic)*25 + tap]);
}

// 5x5 conv pad 2, NHWC bf16, guarded input (round-2 structure: 128oc x 128w block,
// 4 waves of 64x64, single-buffered LDS, 66.5 KB -> 2 blocks/CU whose staggered
// phases provide the overlap; this empirically beats explicit pipelining here).
// + T5 setprio around the MFMA cluster (independent-blocks regime).
template<int IC, int OC, int H>
__global__ __launch_bounds__(256,2) void conv5x5(const u16* __restrict__ in, const u16* __restrict__ wp,
    const float* __restrict__ bias, u16* __restrict__ out){
  constexpr int NICB = IC/128;
  __shared__ u16 sIn[132*128];   // rows 0..131 = input w0-2 .. w0+129, 256B/row, chunk-swizzled
  __shared__ u16 sW[128*128];    // rows = oc local, chunk-swizzled
  int t = threadIdx.x;
  int wave = t >> 6, lane = t & 63, lr = lane & 15, lgp = lane >> 4;
  int w0  = blockIdx.x * 128;
  int ocb = blockIdx.y * 128;
  int nh = blockIdx.z; int n = nh / H, h = nh % H;
  int wo_oc = (wave & 1)*64, wo_w = (wave >> 1)*64;
  f32x4 acc[4][4] = {};
  const u16* inN = in + (size_t)n*H*WST*IC;   // col0 = w=-2
  for (int dh = 0; dh < 5; ++dh){
    int hin = h + dh - 2;
    if (hin < 0 || hin >= H) continue;
    const u16* rowbase = inN + (size_t)hin*WST*IC;
    for (int icb = 0; icb < NICB; ++icb){
      __syncthreads();  // prior reads of sIn/sW done before overwrite
      // stage sIn: 132 rows x 16 chunks = 2112 chunks = 33 gll instrs
      for (int i = wave; i < 33; i += 4){
        int qq = i*64 + lane;
        int r = qq >> 4, cp = qq & 15;
        int c = cp ^ (r & 7);
        gll16(rowbase + (size_t)(w0 + r)*IC + icb*128 + c*8, &sIn[i*512]);
      }
      for (int dw = 0; dw < 5; ++dw){
        if (dw) __syncthreads();  // waves done reading previous sW
        {
          int tap = dh*5 + dw;
          const u16* wsrc = wp + ((size_t)tap*OC + ocb)*IC + (size_t)icb*128;
          for (int i = wave; i < 32; i += 4){
            int qq = i*64 + lane;
            int r = qq >> 4, cp = qq & 15;
            int c = cp ^ (r & 7);
            gll16(wsrc + (size_t)r*IC + c*8, &sW[i*512]);
          }
        }
        __syncthreads();  // staging complete (vmcnt drained by barrier)
        __builtin_amdgcn_s_setprio(1);
        #pragma unroll
        for (int k0i = 0; k0i < 4; ++k0i){
          bf16x8 A[4], B[4];
          #pragma unroll
          for (int j = 0; j < 4; ++j){
            int ar = wo_oc + j*16 + lr;
            A[j] = *(const bf16x8*)&sW[ar*128 + (((k0i*4 + lgp) ^ (lr & 7)) << 3)];
            int br = wo_w + j*16 + lr + dw;
            B[j] = *(const bf16x8*)&sIn[br*128 + (((k0i*4 + lgp) ^ (br & 7)) << 3)];
          }
          #pragma unroll
          for (int ja = 0; ja < 4; ++ja)
            #pragma unroll
            for (int jb = 0; jb < 4; ++jb)
              acc[ja][jb] = __builtin_amdgcn_mfma_f32_16x16x32_bf16(A[ja], B[jb], acc[ja][jb], 0, 0, 0);
        }
        __builtin_amdgcn_s_setprio(0);
      }
    }
  }
  u16* outP = out + ((size_t)(n*H + h)*WST + 2)*OC;  // col = w+2
  #pragma unroll
  for (int ja = 0; ja < 4; ++ja){
    int oc = ocb + wo_oc + ja*16 + lgp*4;
    float4 bv = *(const float4*)&bias[oc];
    #pragma unroll
    for (int jb = 0; jb < 4; ++jb){
      int wg = w0 + wo_w + jb*16 + lr;
      if (wg < WPAD){
        f32x4 av = acc[ja][jb];
        ushort4 o;
        o.x = f2bf(av[0] + bv.x);
        o.y = f2bf(av[1] + bv.y);
        o.z = f2bf(av[2] + bv.z);
        o.w = f2bf(av[3] + bv.w);
        *(ushort4*)(outP + (size_t)wg*OC + oc) = o;
      }
    }
  }
}

// leaky(0.2) + maxpool 3x3 stride(3,1); 4 oc/thread (8B loads); writes full guarded range
__global__ __launch_bounds__(256) void pool1k(const u16* __restrict__ in, u16* __restrict__ out){
  int t = threadIdx.x;
  int wb = blockIdx.x*4 + (t >> 6);
  int oc = (t & 63)*4;
  int ho = blockIdx.y, n = blockIdx.z;
  int wo = wb - 2;
  float m0=0.f,m1=0.f,m2=0.f,m3=0.f;
  if (wo >= 0 && wo < WPAD){
    m0=m1=m2=m3=-1e30f;
    #pragma unroll
    for (int kh = 0; kh < 3; ++kh){
      const u16* row = in + ((size_t)(n*HH + ho*3 + kh)*WST + 2)*OC1 + oc;
      #pragma unroll
      for (int kw = 0; kw < 3; ++kw){
        int wi = wo - 1 + kw;
        if (wi >= 0 && wi < WPAD){
          ushort4 v = *(const ushort4*)(row + (size_t)wi*OC1);
          m0 = fmaxf(m0, bf2f(v.x)); m1 = fmaxf(m1, bf2f(v.y));
          m2 = fmaxf(m2, bf2f(v.z)); m3 = fmaxf(m3, bf2f(v.w));
        }
      }
    }
    m0 = (m0>0.f)?m0:0.2f*m0; m1 = (m1>0.f)?m1:0.2f*m1;
    m2 = (m2>0.f)?m2:0.2f*m2; m3 = (m3>0.f)?m3:0.2f*m3;
  }
  ushort4 o; o.x=f2bf(m0); o.y=f2bf(m1); o.z=f2bf(m2); o.w=f2bf(m3);
  *(ushort4*)(out + ((size_t)(n*16 + ho)*WST + wb)*OC1 + oc) = o;
}

// leaky(0.2) + maxpool 4x5 stride(4,1); 4 oc/thread
__global__ __launch_bounds__(256) void pool2k(const u16* __restrict__ in, u16* __restrict__ out){
  int t = threadIdx.x;
  int wb = blockIdx.x*2 + (t >> 7);
  int oc = (t & 127)*4;
  int ho = blockIdx.y, n = blockIdx.z;
  int wo = wb - 2;
  float m0=0.f,m1=0.f,m2=0.f,m3=0.f;
  if (wo >= 0 && wo < WPAD){
    m0=m1=m2=m3=-1e30f;
    #pragma unroll
    for (int kh = 0; kh < 4; ++kh){
      const u16* row = in + ((size_t)(n*16 + ho*4 + kh)*WST + 2)*OC2 + oc;
      #pragma unroll
      for (int kw = 0; kw < 5; ++kw){
        int wi = wo - 2 + kw;
        if (wi >= 0 && wi < WPAD){
          ushort4 v = *(const ushort4*)(row + (size_t)wi*OC2);
          m0 = fmaxf(m0, bf2f(v.x)); m1 = fmaxf(m1, bf2f(v.y));
          m2 = fmaxf(m2, bf2f(v.z)); m3 = fmaxf(m3, bf2f(v.w));
        }
      }
    }
    m0 = (m0>0.f)?m0:0.2f*m0; m1 = (m1>0.f)?m1:0.2f*m1;
    m2 = (m2>0.f)?m2:0.2f*m2; m3 = (m3>0.f)?m3:0.2f*m3;
  }
  ushort4 o; o.x=f2bf(m0); o.y=f2bf(m1); o.z=f2bf(m2); o.w=f2bf(m3);
  *(ushort4*)(out + ((size_t)(n*4 + ho)*WST + wb)*OC2 + oc) = o;
}

// maxpool 1x200 over one h-row, sampled every 30; partials per h -> xfraw [n][t][4][1024]
__global__ __launch_bounds__(256) void pool3k(const u16* __restrict__ in, float* __restrict__ xfraw){
  int tt = blockIdx.x, hh = blockIdx.y, n = blockIdx.z;
  int oc = threadIdx.x*4;
  float m0=-1e30f,m1=-1e30f,m2=-1e30f,m3=-1e30f;
  const u16* row = in + ((size_t)(n*4 + hh)*WST + 2 + 30*tt)*OC3 + oc;
  for (int p = 0; p < 200; ++p){
    ushort4 v = *(const ushort4*)(row + (size_t)p*OC3);
    m0 = fmaxf(m0, bf2f(v.x)); m1 = fmaxf(m1, bf2f(v.y));
    m2 = fmaxf(m2, bf2f(v.z)); m3 = fmaxf(m3, bf2f(v.w));
  }
  float* dst = xfraw + (((size_t)(n*NT + tt))*4 + hh)*OC3 + oc;
  dst[0]=m0; dst[1]=m1; dst[2]=m2; dst[3]=m3;
}

// combine 4 h-partials, L2 normalize -> xf [row][1024]
__global__ __launch_bounds__(256) void xf_norm(const float* __restrict__ xfraw, float* __restrict__ xf){
  int row = blockIdx.x, t = threadIdx.x;
  const float* src = xfraw + (size_t)row*4096;
  float v[4]; float ss = 0.f;
  #pragma unroll
  for (int j = 0; j < 4; ++j){
    float m = src[t + j*256];
    #pragma unroll
    for (int hh = 1; hh < 4; ++hh) m = fmaxf(m, src[hh*1024 + t + j*256]);
    v[j] = m; ss += m*m;
  }
  #pragma unroll
  for (int m = 1; m < 64; m <<= 1) ss += __shfl_xor(ss, m);
  __shared__ float red[4];
  if ((t & 63) == 0) red[t >> 6] = ss;
  __syncthreads();
  float tot = red[0]+red[1]+red[2]+red[3];
  float inv = 1.f/fmaxf(sqrtf(tot), 1e-12f);
  float* dst = xf + (size_t)row*OC3;
  #pragma unroll
  for (int j = 0; j < 4; ++j) dst[t + j*256] = v[j]*inv;
}

// ---- final head: split-K GEMM. part[row][kc][col] = sum_{i in K-chunk kc} feat[row][i]*W[col][i]
// grid (36 kchunks, 30 rowblocks of 4): 1080 blocks -> latency hidden; W is L2/L3-resident.
__global__ __launch_bounds__(256) void mlp_part(const float* __restrict__ vlad, const float* __restrict__ xf,
    const float* __restrict__ W, float* __restrict__ part){
  __shared__ float feat[4][256];
  int kc = blockIdx.x, rb = blockIdx.y, t = threadIdx.x;
  int i0 = kc*256;
  #pragma unroll
  for (int r = 0; r < 4; ++r){
    int row = rb*4 + r;
    int i = i0 + t;
    feat[r][t] = (i < 8192) ? vlad[(size_t)row*8192 + i] : xf[(size_t)row*1024 + (i - 8192)];
  }
  __syncthreads();
  const float* wr = W + (size_t)t*9216 + i0;
  float a0=0.f, a1=0.f, a2=0.f, a3=0.f;
  for (int i = 0; i < 256; i += 4){
    float4 wv = *(const float4*)&wr[i];
    a0 += feat[0][i]*wv.x + feat[0][i+1]*wv.y + feat[0][i+2]*wv.z + feat[0][i+3]*wv.w;
    a1 += feat[1][i]*wv.x + feat[1][i+1]*wv.y + feat[1][i+2]*wv.z + feat[1][i+3]*wv.w;
    a2 += feat[2][i]*wv.x + feat[2][i+1]*wv.y + feat[2][i+2]*wv.z + feat[2][i+3]*wv.w;
    a3 += feat[3][i]*wv.x + feat[3][i+1]*wv.y + feat[3][i+2]*wv.z + feat[3][i+3]*wv.w;
  }
  float* p0 = part + (((size_t)(rb*4 + 0)*36 + kc))*256 + t;
  p0[0]          = a0;
  p0[36*256]     = a1;
  p0[2*36*256]   = a2;
  p0[3*36*256]   = a3;
}

// sum 36 K-chunk partials + bias, L2 normalize, write out. grid 120.
__global__ __launch_bounds__(256) void mlp_reduce(const float* __restrict__ part, const float* __restrict__ b,
    float* __restrict__ out){
  int row = blockIdx.x, t = threadIdx.x;
  const float* pr = part + (size_t)row*36*256 + t;
  float acc = b[t];
  #pragma unroll
  for (int kc = 0; kc < 36; ++kc) acc += pr[kc*256];
  float ss = acc*acc;
  #pragma unroll
  for (int m = 1; m < 64; m <<= 1) ss += __shfl_xor(ss, m);
  __shared__ float red[4];
  if ((t & 63) == 0) red[t >> 6] = ss;
  __syncthreads();
  float tot = red[0]+red[1]+red[2]+red[3];
  float inv = 1.f/fmaxf(sqrtf(tot), 1e-12f);
  out[(size_t)row*256 + t] = acc*inv;
}

// ---------------- launch ----------------
extern "C" void kernel_launch(void* const* d_in, const int* in_sizes, int n_in,
                              void* d_out, int out_size, void* d_ws, size_t ws_size,
                              hipStream_t stream){
  const float* x       = (const float*)d_in[0];
  const float* centers = (const float*)d_in[1];
  const float* conv_w  = (const float*)d_in[2];
  const float* conv_b  = (const float*)d_in[3];
  const float* w1      = (const float*)d_in[4];
  const float* b1      = (const float*)d_in[5];
  const float* w2      = (const float*)d_in[6];
  const float* b2      = (const float*)d_in[7];
  const float* w3      = (const float*)d_in[8];
  const float* b3      = (const float*)d_in[9];
  const float* mlp_w   = (const float*)d_in[10];
  const float* mlp_b   = (const float*)d_in[11];
  float* out = (float*)d_out;
  char* ws = (char*)d_ws;
  const size_t MB = 1ull << 20;
  if (ws_size < 248*MB) return;

  // persistent small buffers
  float* vlad  = (float*)(ws + 0);        // 3.75 MiB
  float* xf    = (float*)(ws + 4*MB);     // 0.47 MiB
  float* xfraw = (float*)(ws + 5*MB);     // 1.97 MiB
  char*  AR    = ws + 7*MB;               // arena (241 MiB), phase-reused
  // VLAD phase
  float* xt = (float*)(AR + 0);           // 84.4 MiB
  float* a  = (float*)(AR + 85*MB);       // 42.2 MiB (dead after vlad_xa2)
  float* ps = (float*)(AR + 128*MB);      // 14.4 MiB (dead after vlad_win2)
  // conv phase (after vlad_win2; regions recycled, stream-ordered)
  u16* xpb = (u16*)(AR + 0);              // 54.4 MiB (over xt)
  u16* wp1 = (u16*)(AR + 55*MB);          // 1.6 MiB
  u16* wp2 = (u16*)(AR + 57*MB);          // 6.25 MiB
  u16* wp3 = (u16*)(AR + 64*MB);          // 25 MiB
  u16* h1  = (u16*)(AR + 89*MB);          // 108.75 MiB (over a/ps)
  u16* p1  = (u16*)(AR + 0);              // 36.25 MiB (over xpb, dead after conv1)
  u16* h2  = (u16*)(AR + 89*MB);          // 72.5 MiB (over h1, dead after pool1)
  u16* p2  = (u16*)(AR + 163*MB);         // 18.1 MiB (past h2)
  u16* h3  = (u16*)(AR + 0);              // 36.25 MiB (over p1, dead after conv2)
  float* part = (float*)(AR + 200*MB);    // 4.4 MiB (head split-K partials)

  // ---- VLAD (fp32) ----
  transpose_xt<<<dim3(29,192,NB), 256, 0, stream>>>(x, xt);
  vlad_softmax<<<dim3(4,HH,NB), 256, 0, stream>>>(x, conv_w, conv_b, a);
  vlad_xa2<<<dim3(110,NB), 256, 0, stream>>>(xt, a, centers, ps);
  vlad_win2<<<dim3(KC,NT,NB), 128, 0, stream>>>(ps, vlad);
  vlad_gnorm<<<dim3(NB*NT), 256, 0, stream>>>(vlad);

  // ---- conv tower (bf16 MFMA) ----
  pack_w<<<dim3(3200),  256, 0, stream>>>(w1, wp1, OC1, DIM);
  pack_w<<<dim3(12800), 256, 0, stream>>>(w2, wp2, OC2, OC1);
  pack_w<<<dim3(51200), 256, 0, stream>>>(w3, wp3, OC3, OC2);
  build_xpb<<<dim3(37,HH,NB), 256, 0, stream>>>(x, xpb);
  conv5x5<128,256,48><<<dim3(9, OC1/128, NB*HH), 256, 0, stream>>>(xpb, wp1, b1, h1);
  pool1k<<<dim3(WST/4,16,NB), 256, 0, stream>>>(h1, p1);
  conv5x5<256,512,16><<<dim3(9, OC2/128, NB*16), 256, 0, stream>>>(p1, wp2, b2, h2);
  pool2k<<<dim3(WST/2,4,NB), 256, 0, stream>>>(h2, p2);
  conv5x5<512,1024,4><<<dim3(9, OC3/128, NB*4), 256, 0, stream>>>(p2, wp3, b3, h3);
  pool3k<<<dim3(NT,4,NB), 256, 0, stream>>>(h3, xfraw);
  xf_norm<<<dim3(NB*NT), 256, 0, stream>>>(xfraw, xf);

  // ---- head (split-K) ----
  mlp_part<<<dim3(36,30), 256, 0, stream>>>(vlad, xf, mlp_w, part);
  mlp_reduce<<<dim3(NB*NT), 256, 0, stream>>>(part, mlp_b, out);
}